// Round 1
// baseline (451.390 us; speedup 1.0000x reference)
//
#include <hip/hip_runtime.h>
#include <hip/hip_bf16.h>
#include <math.h>

#define N_NODES 50000
#define N_EDGES 600000
#define TOT_E   (N_EDGES + N_NODES)   // with self loops
#define FDIM    128
#define NCLS    40
#define SCAN_B  1024

// ---------------- reductions ----------------
__device__ inline float block_reduce_sum128(float v, float* red, int tid) {
    #pragma unroll
    for (int off = 32; off > 0; off >>= 1) v += __shfl_down(v, off, 64);
    if ((tid & 63) == 0) red[tid >> 6] = v;
    __syncthreads();
    float r = red[0] + red[1];
    __syncthreads();
    return r;
}

__device__ inline float block_reduce_max128(float v, float* red, int tid) {
    #pragma unroll
    for (int off = 32; off > 0; off >>= 1) v = fmaxf(v, __shfl_down(v, off, 64));
    if ((tid & 63) == 0) red[tid >> 6] = v;
    __syncthreads();
    float r = fmaxf(red[0], red[1]);
    __syncthreads();
    return r;
}

// ---------------- CSR build ----------------
__global__ void hist_kernel(const int* __restrict__ ei, int* __restrict__ counts) {
    int e = blockIdx.x * blockDim.x + threadIdx.x;
    if (e >= TOT_E) return;
    int d = (e < N_EDGES) ? ei[N_EDGES + e] : (e - N_EDGES);
    atomicAdd(&counts[d], 1);
}

__global__ void scan1_kernel(const int* __restrict__ counts, int* __restrict__ excl,
                             int* __restrict__ bsums, int n) {
    __shared__ int buf[SCAN_B];
    int gid = blockIdx.x * SCAN_B + threadIdx.x;
    int v = (gid < n) ? counts[gid] : 0;
    buf[threadIdx.x] = v;
    __syncthreads();
    for (int off = 1; off < SCAN_B; off <<= 1) {
        int t = (threadIdx.x >= off) ? buf[threadIdx.x - off] : 0;
        __syncthreads();
        buf[threadIdx.x] += t;
        __syncthreads();
    }
    if (gid < n) excl[gid] = buf[threadIdx.x] - v;  // exclusive
    if (threadIdx.x == SCAN_B - 1) bsums[blockIdx.x] = buf[threadIdx.x];
}

__global__ void scan2_kernel(int* __restrict__ bsums, int nb) {
    if (blockIdx.x == 0 && threadIdx.x == 0) {
        int run = 0;
        for (int i = 0; i < nb; i++) { int t = bsums[i]; bsums[i] = run; run += t; }
    }
}

__global__ void scan3_kernel(int* __restrict__ rowptr, const int* __restrict__ bsums,
                             int* __restrict__ cursor, int n, int total) {
    int gid = blockIdx.x * SCAN_B + threadIdx.x;
    if (gid < n) {
        int v = rowptr[gid] + bsums[blockIdx.x];
        rowptr[gid] = v;
        cursor[gid] = v;
    }
    if (gid == 0) rowptr[n] = total;
}

__global__ void scatter_kernel(const int* __restrict__ ei, int* __restrict__ cursor,
                               int* __restrict__ adj) {
    int e = blockIdx.x * blockDim.x + threadIdx.x;
    if (e >= TOT_E) return;
    int s, d;
    if (e < N_EDGES) { s = ei[e]; d = ei[N_EDGES + e]; }
    else             { s = e - N_EDGES; d = s; }
    int pos = atomicAdd(&cursor[d], 1);
    adj[pos] = s;
}

// ---------------- GEMM (h = X @ W) + attention scores ----------------
// 8 rows per block, 128 threads; thread t owns output column t.
__global__ void gemm_att_kernel(const float* __restrict__ X, const float* __restrict__ W,
                                const float* __restrict__ asrc, const float* __restrict__ adst,
                                float* __restrict__ H, float* __restrict__ ssrc,
                                float* __restrict__ sdst) {
    __shared__ float xs[8][FDIM];
    __shared__ float red[2];
    int tid  = threadIdx.x;
    int row0 = blockIdx.x * 8;
    #pragma unroll
    for (int r = 0; r < 8; r++) xs[r][tid] = X[(size_t)(row0 + r) * FDIM + tid];
    __syncthreads();

    float acc[8] = {0.f, 0.f, 0.f, 0.f, 0.f, 0.f, 0.f, 0.f};
    #pragma unroll 4
    for (int k = 0; k < FDIM; k++) {
        float w = W[k * FDIM + tid];
        #pragma unroll
        for (int r = 0; r < 8; r++) acc[r] += xs[r][k] * w;
    }

    float va = asrc[tid], vd = adst[tid];
    for (int r = 0; r < 8; r++) {
        H[(size_t)(row0 + r) * FDIM + tid] = acc[r];
        float s1 = block_reduce_sum128(acc[r] * va, red, tid);
        float s2 = block_reduce_sum128(acc[r] * vd, red, tid);
        if (tid == 0) { ssrc[row0 + r] = s1; sdst[row0 + r] = s2; }
    }
}

// ---------------- per-dst softmax + aggregation ----------------
// One block (128 threads) per destination node. No atomics.
#define CHUNK 256
__global__ void gat_aggregate(const float* __restrict__ h, const float* __restrict__ ssrc,
                              const float* __restrict__ sdst, const int* __restrict__ rowptr,
                              const int* __restrict__ adj, const float* __restrict__ bias,
                              float* __restrict__ out, int do_relu) {
    int n = blockIdx.x, tid = threadIdx.x;
    __shared__ float red[2];
    __shared__ float wbuf[CHUNK];
    int beg = rowptr[n], end = rowptr[n + 1];
    int deg = end - beg;               // >= 1 (self loop)
    float sd = sdst[n];

    // pass 1: segment max of leaky_relu(ssrc[src] + sd)
    float lm = -INFINITY;
    for (int j = tid; j < deg; j += 128) {
        float e = ssrc[adj[beg + j]] + sd;
        e = (e >= 0.f) ? e : 0.2f * e;
        lm = fmaxf(lm, e);
    }
    float m = block_reduce_max128(lm, red, tid);

    // pass 2: chunked exp weights into LDS; accumulate unnormalized output
    float acc = 0.f, dsum = 0.f;
    for (int base = 0; base < deg; base += CHUNK) {
        int c = min(CHUNK, deg - base);
        __syncthreads();
        for (int j = tid; j < c; j += 128) {
            float e = ssrc[adj[beg + base + j]] + sd;
            e = (e >= 0.f) ? e : 0.2f * e;
            float w = expf(e - m);
            wbuf[j] = w;
            dsum += w;
        }
        __syncthreads();
        for (int j = 0; j < c; j++) {
            int s = adj[beg + base + j];     // broadcast load
            acc += wbuf[j] * h[(size_t)s * FDIM + tid];
        }
    }
    __syncthreads();
    float denom = block_reduce_sum128(dsum, red, tid);
    float v = acc / denom + bias[tid];
    if (do_relu) v = fmaxf(v, 0.f);
    out[(size_t)n * FDIM + tid] = v;
}

// ---------------- classifier: log_softmax(H @ Wl + bl) ----------------
__global__ void classifier_kernel(const float* __restrict__ H, const float* __restrict__ Wl,
                                  const float* __restrict__ bl, float* __restrict__ out) {
    int n = blockIdx.x, lane = threadIdx.x;   // 64 threads
    __shared__ float hs[FDIM];
    hs[lane]      = H[(size_t)n * FDIM + lane];
    hs[lane + 64] = H[(size_t)n * FDIM + 64 + lane];
    __syncthreads();

    float acc = -INFINITY;
    if (lane < NCLS) {
        acc = bl[lane];
        #pragma unroll 4
        for (int k = 0; k < FDIM; k++) acc += hs[k] * Wl[k * NCLS + lane];
    }
    float m = acc;
    #pragma unroll
    for (int off = 32; off > 0; off >>= 1) m = fmaxf(m, __shfl_xor(m, off, 64));
    float ex = (lane < NCLS) ? expf(acc - m) : 0.f;
    #pragma unroll
    for (int off = 32; off > 0; off >>= 1) ex += __shfl_xor(ex, off, 64);
    float lse = logf(ex);
    if (lane < NCLS) out[(size_t)n * NCLS + lane] = acc - m - lse;
}

// ---------------- edge_index pass-through (as f32) ----------------
__global__ void edge_copy_kernel(const int* __restrict__ ei, float* __restrict__ out) {
    int i = blockIdx.x * blockDim.x + threadIdx.x;
    if (i < 2 * N_EDGES) out[i] = (float)ei[i];
}

extern "C" void kernel_launch(void* const* d_in, const int* in_sizes, int n_in,
                              void* d_out, int out_size, void* d_ws, size_t ws_size,
                              hipStream_t stream) {
    const float* x   = (const float*)d_in[0];
    const int*   ei  = (const int*)d_in[1];
    const float* W1  = (const float*)d_in[2];
    const float* a1s = (const float*)d_in[3];
    const float* a1d = (const float*)d_in[4];
    const float* b1  = (const float*)d_in[5];
    const float* W2  = (const float*)d_in[6];
    const float* a2s = (const float*)d_in[7];
    const float* a2d = (const float*)d_in[8];
    const float* b2  = (const float*)d_in[9];
    const float* Wl  = (const float*)d_in[10];
    const float* bl  = (const float*)d_in[11];
    float* out = (float*)d_out;

    char* ws = (char*)d_ws;
    size_t off = 0;
    auto alloc = [&](size_t bytes) {
        void* p = ws + off;
        off = (off + bytes + 255) & ~(size_t)255;
        return p;
    };
    int*   row_ptr = (int*)alloc((N_NODES + 1) * sizeof(int));
    int*   cursor  = (int*)alloc(N_NODES * sizeof(int));
    int*   counts  = (int*)alloc(N_NODES * sizeof(int));
    int*   bsums   = (int*)alloc(64 * sizeof(int));
    int*   adj     = (int*)alloc(TOT_E * sizeof(int));
    float* hA      = (float*)alloc((size_t)N_NODES * FDIM * sizeof(float));
    float* hB      = (float*)alloc((size_t)N_NODES * FDIM * sizeof(float));
    float* ssrc    = (float*)alloc(N_NODES * sizeof(float));
    float* sdst    = (float*)alloc(N_NODES * sizeof(float));

    // ---- CSR build (fixed graph, rebuilt every call: no static state) ----
    hipMemsetAsync(counts, 0, N_NODES * sizeof(int), stream);
    {
        int thr = 256, grid = (TOT_E + thr - 1) / thr;
        hipLaunchKernelGGL(hist_kernel, dim3(grid), dim3(thr), 0, stream, ei, counts);
    }
    int nscan = (N_NODES + SCAN_B - 1) / SCAN_B;  // 49
    hipLaunchKernelGGL(scan1_kernel, dim3(nscan), dim3(SCAN_B), 0, stream, counts, row_ptr, bsums, N_NODES);
    hipLaunchKernelGGL(scan2_kernel, dim3(1), dim3(64), 0, stream, bsums, nscan);
    hipLaunchKernelGGL(scan3_kernel, dim3(nscan), dim3(SCAN_B), 0, stream, row_ptr, bsums, cursor, N_NODES, TOT_E);
    {
        int thr = 256, grid = (TOT_E + thr - 1) / thr;
        hipLaunchKernelGGL(scatter_kernel, dim3(grid), dim3(thr), 0, stream, ei, cursor, adj);
    }

    // ---- layer 1 ----
    hipLaunchKernelGGL(gemm_att_kernel, dim3(N_NODES / 8), dim3(FDIM), 0, stream,
                       x, W1, a1s, a1d, hA, ssrc, sdst);
    hipLaunchKernelGGL(gat_aggregate, dim3(N_NODES), dim3(FDIM), 0, stream,
                       hA, ssrc, sdst, row_ptr, adj, b1, hB, 1);

    // ---- layer 2 ----
    hipLaunchKernelGGL(gemm_att_kernel, dim3(N_NODES / 8), dim3(FDIM), 0, stream,
                       hB, W2, a2s, a2d, hA, ssrc, sdst);
    hipLaunchKernelGGL(gat_aggregate, dim3(N_NODES), dim3(FDIM), 0, stream,
                       hA, ssrc, sdst, row_ptr, adj, b2, hB, 0);

    // ---- classifier + edge pass-through ----
    hipLaunchKernelGGL(classifier_kernel, dim3(N_NODES), dim3(64), 0, stream, hB, Wl, bl, out);
    {
        int thr = 256, grid = (2 * N_EDGES + thr - 1) / thr;
        hipLaunchKernelGGL(edge_copy_kernel, dim3(grid), dim3(thr), 0, stream,
                           ei, out + (size_t)N_NODES * NCLS);
    }
}

// Round 2
// 410.892 us; speedup vs baseline: 1.0986x; 1.0986x over previous
//
#include <hip/hip_runtime.h>
#include <hip/hip_bf16.h>
#include <math.h>

#define N_NODES 50000
#define N_EDGES 600000
#define TOT_E   (N_EDGES + N_NODES)   // with self loops
#define FDIM    128
#define NCLS    40
#define SCAN_B  1024

// ---------------- reductions ----------------
__device__ inline float block_reduce_sum128(float v, float* red, int tid) {
    #pragma unroll
    for (int off = 32; off > 0; off >>= 1) v += __shfl_down(v, off, 64);
    if ((tid & 63) == 0) red[tid >> 6] = v;
    __syncthreads();
    float r = red[0] + red[1];
    __syncthreads();
    return r;
}

__device__ inline float block_reduce_max128(float v, float* red, int tid) {
    #pragma unroll
    for (int off = 32; off > 0; off >>= 1) v = fmaxf(v, __shfl_down(v, off, 64));
    if ((tid & 63) == 0) red[tid >> 6] = v;
    __syncthreads();
    float r = fmaxf(red[0], red[1]);
    __syncthreads();
    return r;
}

// ---------------- CSR build ----------------
__global__ void hist_kernel(const int* __restrict__ ei, int* __restrict__ counts) {
    int e = blockIdx.x * blockDim.x + threadIdx.x;
    if (e >= TOT_E) return;
    int d = (e < N_EDGES) ? ei[N_EDGES + e] : (e - N_EDGES);
    atomicAdd(&counts[d], 1);
}

__global__ void scan1_kernel(const int* __restrict__ counts, int* __restrict__ excl,
                             int* __restrict__ bsums, int n) {
    __shared__ int buf[SCAN_B];
    int gid = blockIdx.x * SCAN_B + threadIdx.x;
    int v = (gid < n) ? counts[gid] : 0;
    buf[threadIdx.x] = v;
    __syncthreads();
    for (int off = 1; off < SCAN_B; off <<= 1) {
        int t = (threadIdx.x >= off) ? buf[threadIdx.x - off] : 0;
        __syncthreads();
        buf[threadIdx.x] += t;
        __syncthreads();
    }
    if (gid < n) excl[gid] = buf[threadIdx.x] - v;  // exclusive within block
    if (threadIdx.x == SCAN_B - 1) bsums[blockIdx.x] = buf[threadIdx.x];
}

// scan3 now also computes its own block-prefix from bsums (scan2 folded in).
__global__ void scan3_kernel(int* __restrict__ rowptr, const int* __restrict__ bsums,
                             int* __restrict__ cursor, int n, int total) {
    __shared__ int base_s;
    if (threadIdx.x < 64) {
        int v = (threadIdx.x < (int)blockIdx.x) ? bsums[threadIdx.x] : 0;
        #pragma unroll
        for (int off = 32; off > 0; off >>= 1) v += __shfl_down(v, off, 64);
        if (threadIdx.x == 0) base_s = v;
    }
    __syncthreads();
    int base = base_s;
    int gid = blockIdx.x * SCAN_B + threadIdx.x;
    if (gid < n) {
        int v = rowptr[gid] + base;
        rowptr[gid] = v;
        cursor[gid] = v;
    }
    if (gid == 0) rowptr[n] = total;
}

__global__ void scatter_kernel(const int* __restrict__ ei, int* __restrict__ cursor,
                               int* __restrict__ adj) {
    int e = blockIdx.x * blockDim.x + threadIdx.x;
    if (e >= TOT_E) return;
    int s, d;
    if (e < N_EDGES) { s = ei[e]; d = ei[N_EDGES + e]; }
    else             { s = e - N_EDGES; d = s; }
    int pos = atomicAdd(&cursor[d], 1);
    adj[pos] = s;
}

// ---------------- precompute Wa = W @ a  (s = h@a == x@(W@a)) ----------------
__global__ void prep_wa(const float* __restrict__ W1, const float* __restrict__ a1s,
                        const float* __restrict__ a1d, const float* __restrict__ W2,
                        const float* __restrict__ a2s, const float* __restrict__ a2d,
                        float* __restrict__ wa) {
    int t = threadIdx.x;          // 512 threads, 1 block
    int vec = t >> 7, k = t & 127;
    const float* W = (vec < 2) ? W1 : W2;
    const float* a = (vec == 0) ? a1s : (vec == 1) ? a1d : (vec == 2) ? a2s : a2d;
    float s = 0.f;
    #pragma unroll 4
    for (int j = 0; j < FDIM; j += 4) {
        float4 wv = *(const float4*)&W[k * FDIM + j];
        float4 av = *(const float4*)&a[j];
        s += wv.x * av.x + wv.y * av.y + wv.z * av.z + wv.w * av.w;
    }
    wa[vec * FDIM + k] = s;
}

// ---------------- GEMM (h = X @ W) + fused attention scores ----------------
// 16 rows per block, 128 threads; thread t owns output column t.
#define GR 16
__global__ __launch_bounds__(128) void gemm_att_kernel(
        const float* __restrict__ X, const float* __restrict__ W,
        const float* __restrict__ wa_s, const float* __restrict__ wa_d,
        float* __restrict__ H, float* __restrict__ ssrc, float* __restrict__ sdst) {
    __shared__ float xs[GR][FDIM];
    int tid  = threadIdx.x;
    int row0 = blockIdx.x * GR;

    const float4* Xv = (const float4*)(X + (size_t)row0 * FDIM);
    float4* xsv = (float4*)&xs[0][0];
    #pragma unroll
    for (int i = 0; i < 4; i++) xsv[tid + 128 * i] = Xv[tid + 128 * i];
    __syncthreads();

    float acc[GR];
    #pragma unroll
    for (int r = 0; r < GR; r++) acc[r] = 0.f;

    #pragma unroll 2
    for (int k = 0; k < FDIM; k += 4) {
        float w0 = W[(k + 0) * FDIM + tid];
        float w1 = W[(k + 1) * FDIM + tid];
        float w2 = W[(k + 2) * FDIM + tid];
        float w3 = W[(k + 3) * FDIM + tid];
        #pragma unroll
        for (int r = 0; r < GR; r++) {
            float4 xv = *(const float4*)&xs[r][k];   // LDS broadcast b128
            acc[r] += xv.x * w0 + xv.y * w1 + xv.z * w2 + xv.w * w3;
        }
    }
    #pragma unroll
    for (int r = 0; r < GR; r++)
        H[(size_t)(row0 + r) * FDIM + tid] = acc[r];

    // fused scores: slot = (row, src/dst), 4 lanes per slot
    int slot = tid >> 2, q = tid & 3;
    int r = slot >> 1;
    const float* av = (slot & 1) ? wa_d : wa_s;
    float p = 0.f;
    #pragma unroll
    for (int k = q * 32; k < q * 32 + 32; k += 4) {
        float4 xv = *(const float4*)&xs[r][k];
        p += xv.x * av[k] + xv.y * av[k + 1] + xv.z * av[k + 2] + xv.w * av[k + 3];
    }
    p += __shfl_down(p, 1, 4);
    p += __shfl_down(p, 2, 4);
    if (q == 0) { if (slot & 1) sdst[row0 + r] = p; else ssrc[row0 + r] = p; }
}

// ---------------- per-dst softmax + aggregation ----------------
// One block (128 threads) per destination node: 4 edge-groups x 32 lanes, float4.
#define CHUNK 128
__global__ __launch_bounds__(128) void gat_aggregate(
        const float* __restrict__ h, const float* __restrict__ ssrc,
        const float* __restrict__ sdst, const int* __restrict__ rowptr,
        const int* __restrict__ adj, const float* __restrict__ bias,
        float* __restrict__ out, int do_relu) {
    int n = blockIdx.x, tid = threadIdx.x;
    int g = tid >> 5, lane = tid & 31;
    __shared__ float red[2];
    __shared__ float wbuf[CHUNK];
    __shared__ int   sbuf[CHUNK];
    __shared__ float sacc[4][FDIM];
    int beg = rowptr[n], deg = rowptr[n + 1] - beg;  // >= 1 (self loop)
    float sd = sdst[n];

    // pass 1: segment max of leaky_relu(ssrc[src] + sd)
    float lm = -INFINITY;
    for (int j = tid; j < deg; j += 128) {
        float e = ssrc[adj[beg + j]] + sd;
        e = (e >= 0.f) ? e : 0.2f * e;
        lm = fmaxf(lm, e);
    }
    float m = block_reduce_max128(lm, red, tid);

    const float4* hv = (const float4*)h;
    float4 acc = make_float4(0.f, 0.f, 0.f, 0.f);
    float dsum = 0.f;
    for (int base = 0; base < deg; base += CHUNK) {
        int c = min(CHUNK, deg - base);
        __syncthreads();
        for (int j = tid; j < c; j += 128) {
            int s = adj[beg + base + j];
            float e = ssrc[s] + sd;
            e = (e >= 0.f) ? e : 0.2f * e;
            float w = expf(e - m);
            wbuf[j] = w; sbuf[j] = s;
            dsum += w;
        }
        __syncthreads();
        int j = g;
        for (; j + 4 < c; j += 8) {       // 2 edges per group iter -> 8 rows in flight/block
            int   s0 = sbuf[j],     s1 = sbuf[j + 4];
            float w0 = wbuf[j],     w1 = wbuf[j + 4];
            float4 h0 = hv[(size_t)s0 * (FDIM / 4) + lane];
            float4 h1 = hv[(size_t)s1 * (FDIM / 4) + lane];
            acc.x += w0 * h0.x + w1 * h1.x;
            acc.y += w0 * h0.y + w1 * h1.y;
            acc.z += w0 * h0.z + w1 * h1.z;
            acc.w += w0 * h0.w + w1 * h1.w;
        }
        for (; j < c; j += 4) {
            int s = sbuf[j]; float w = wbuf[j];
            float4 hx = hv[(size_t)s * (FDIM / 4) + lane];
            acc.x += w * hx.x; acc.y += w * hx.y; acc.z += w * hx.z; acc.w += w * hx.w;
        }
    }
    __syncthreads();
    float denom = block_reduce_sum128(dsum, red, tid);
    sacc[g][lane * 4 + 0] = acc.x;
    sacc[g][lane * 4 + 1] = acc.y;
    sacc[g][lane * 4 + 2] = acc.z;
    sacc[g][lane * 4 + 3] = acc.w;
    __syncthreads();
    float v = sacc[0][tid] + sacc[1][tid] + sacc[2][tid] + sacc[3][tid];
    v = v / denom + bias[tid];
    if (do_relu) v = fmaxf(v, 0.f);
    out[(size_t)n * FDIM + tid] = v;
}

// ---------------- classifier: log_softmax(H @ Wl + bl), 16 rows/block ----------------
__global__ __launch_bounds__(128) void classifier_kernel(
        const float* __restrict__ H, const float* __restrict__ Wl,
        const float* __restrict__ bl, float* __restrict__ out) {
    __shared__ float xs[16][FDIM];
    int tid  = threadIdx.x;
    int row0 = blockIdx.x * 16;
    const float4* Hv = (const float4*)(H + (size_t)row0 * FDIM);
    float4* xsv = (float4*)&xs[0][0];
    #pragma unroll
    for (int i = 0; i < 4; i++) xsv[tid + 128 * i] = Hv[tid + 128 * i];
    __syncthreads();

    int c = tid & 63, hw = tid >> 6;    // wave hw handles rows hw*8 .. hw*8+7
    float acc[8];
    float blc = (c < NCLS) ? bl[c] : 0.f;
    #pragma unroll
    for (int r = 0; r < 8; r++) acc[r] = blc;

    #pragma unroll 2
    for (int k = 0; k < FDIM; k += 4) {
        float w0 = 0.f, w1 = 0.f, w2 = 0.f, w3 = 0.f;
        if (c < NCLS) {
            w0 = Wl[(k + 0) * NCLS + c]; w1 = Wl[(k + 1) * NCLS + c];
            w2 = Wl[(k + 2) * NCLS + c]; w3 = Wl[(k + 3) * NCLS + c];
        }
        #pragma unroll
        for (int r = 0; r < 8; r++) {
            float4 xv = *(const float4*)&xs[hw * 8 + r][k];
            acc[r] += xv.x * w0 + xv.y * w1 + xv.z * w2 + xv.w * w3;
        }
    }
    #pragma unroll
    for (int r = 0; r < 8; r++) {
        float v = (c < NCLS) ? acc[r] : -INFINITY;
        float mx = v;
        #pragma unroll
        for (int off = 32; off > 0; off >>= 1) mx = fmaxf(mx, __shfl_xor(mx, off, 64));
        float ex = (c < NCLS) ? expf(v - mx) : 0.f;
        #pragma unroll
        for (int off = 32; off > 0; off >>= 1) ex += __shfl_xor(ex, off, 64);
        float ls = logf(ex);
        if (c < NCLS) out[(size_t)(row0 + hw * 8 + r) * NCLS + c] = v - mx - ls;
    }
}

// ---------------- edge_index pass-through (as f32), vectorized ----------------
__global__ void edge_copy_kernel(const int* __restrict__ ei, float* __restrict__ out) {
    int i = blockIdx.x * blockDim.x + threadIdx.x;
    if (i >= (2 * N_EDGES) / 4) return;
    int4 v = ((const int4*)ei)[i];
    float4 f = make_float4((float)v.x, (float)v.y, (float)v.z, (float)v.w);
    ((float4*)out)[i] = f;
}

extern "C" void kernel_launch(void* const* d_in, const int* in_sizes, int n_in,
                              void* d_out, int out_size, void* d_ws, size_t ws_size,
                              hipStream_t stream) {
    const float* x   = (const float*)d_in[0];
    const int*   ei  = (const int*)d_in[1];
    const float* W1  = (const float*)d_in[2];
    const float* a1s = (const float*)d_in[3];
    const float* a1d = (const float*)d_in[4];
    const float* b1  = (const float*)d_in[5];
    const float* W2  = (const float*)d_in[6];
    const float* a2s = (const float*)d_in[7];
    const float* a2d = (const float*)d_in[8];
    const float* b2  = (const float*)d_in[9];
    const float* Wl  = (const float*)d_in[10];
    const float* bl  = (const float*)d_in[11];
    float* out = (float*)d_out;

    char* ws = (char*)d_ws;
    size_t off = 0;
    auto alloc = [&](size_t bytes) {
        void* p = ws + off;
        off = (off + bytes + 255) & ~(size_t)255;
        return p;
    };
    int*   row_ptr = (int*)alloc((N_NODES + 1) * sizeof(int));
    int*   cursor  = (int*)alloc(N_NODES * sizeof(int));
    int*   counts  = (int*)alloc(N_NODES * sizeof(int));
    int*   bsums   = (int*)alloc(64 * sizeof(int));
    int*   adj     = (int*)alloc(TOT_E * sizeof(int));
    float* hA      = (float*)alloc((size_t)N_NODES * FDIM * sizeof(float));
    float* hB      = (float*)alloc((size_t)N_NODES * FDIM * sizeof(float));
    float* ssrc    = (float*)alloc(N_NODES * sizeof(float));
    float* sdst    = (float*)alloc(N_NODES * sizeof(float));
    float* wa      = (float*)alloc(4 * FDIM * sizeof(float));

    // ---- Wa precompute (independent) ----
    hipLaunchKernelGGL(prep_wa, dim3(1), dim3(512), 0, stream, W1, a1s, a1d, W2, a2s, a2d, wa);

    // ---- CSR build ----
    hipMemsetAsync(counts, 0, N_NODES * sizeof(int), stream);
    {
        int thr = 256, grid = (TOT_E + thr - 1) / thr;
        hipLaunchKernelGGL(hist_kernel, dim3(grid), dim3(thr), 0, stream, ei, counts);
    }
    int nscan = (N_NODES + SCAN_B - 1) / SCAN_B;  // 49
    hipLaunchKernelGGL(scan1_kernel, dim3(nscan), dim3(SCAN_B), 0, stream, counts, row_ptr, bsums, N_NODES);
    hipLaunchKernelGGL(scan3_kernel, dim3(nscan), dim3(SCAN_B), 0, stream, row_ptr, bsums, cursor, N_NODES, TOT_E);
    {
        int thr = 256, grid = (TOT_E + thr - 1) / thr;
        hipLaunchKernelGGL(scatter_kernel, dim3(grid), dim3(thr), 0, stream, ei, cursor, adj);
    }

    // ---- layer 1 ----
    hipLaunchKernelGGL(gemm_att_kernel, dim3(N_NODES / GR), dim3(128), 0, stream,
                       x, W1, wa + 0, wa + FDIM, hA, ssrc, sdst);
    hipLaunchKernelGGL(gat_aggregate, dim3(N_NODES), dim3(128), 0, stream,
                       hA, ssrc, sdst, row_ptr, adj, b1, hB, 1);

    // ---- layer 2 ----
    hipLaunchKernelGGL(gemm_att_kernel, dim3(N_NODES / GR), dim3(128), 0, stream,
                       hB, W2, wa + 2 * FDIM, wa + 3 * FDIM, hA, ssrc, sdst);
    hipLaunchKernelGGL(gat_aggregate, dim3(N_NODES), dim3(128), 0, stream,
                       hA, ssrc, sdst, row_ptr, adj, b2, hB, 0);

    // ---- classifier + edge pass-through ----
    hipLaunchKernelGGL(classifier_kernel, dim3(N_NODES / 16), dim3(128), 0, stream, hB, Wl, bl, out);
    {
        int thr = 256, grid = ((2 * N_EDGES) / 4 + thr - 1) / thr;
        hipLaunchKernelGGL(edge_copy_kernel, dim3(grid), dim3(thr), 0, stream,
                           ei, out + (size_t)N_NODES * NCLS);
    }
}

// Round 3
// 376.129 us; speedup vs baseline: 1.2001x; 1.0924x over previous
//
#include <hip/hip_runtime.h>
#include <hip/hip_bf16.h>
#include <math.h>

#define N_NODES 50000
#define N_EDGES 600000
#define TOT_E   (N_EDGES + N_NODES)   // with self loops
#define FDIM    128
#define NCLS    40
#define SCAN_B  1024

// ---------------- CSR build ----------------
__global__ void hist_kernel(const int* __restrict__ ei, int* __restrict__ counts) {
    int e = blockIdx.x * blockDim.x + threadIdx.x;
    if (e >= TOT_E) return;
    int d = (e < N_EDGES) ? ei[N_EDGES + e] : (e - N_EDGES);
    atomicAdd(&counts[d], 1);
}

__global__ void scan1_kernel(const int* __restrict__ counts, int* __restrict__ excl,
                             int* __restrict__ bsums, int n) {
    __shared__ int buf[SCAN_B];
    int gid = blockIdx.x * SCAN_B + threadIdx.x;
    int v = (gid < n) ? counts[gid] : 0;
    buf[threadIdx.x] = v;
    __syncthreads();
    for (int off = 1; off < SCAN_B; off <<= 1) {
        int t = (threadIdx.x >= off) ? buf[threadIdx.x - off] : 0;
        __syncthreads();
        buf[threadIdx.x] += t;
        __syncthreads();
    }
    if (gid < n) excl[gid] = buf[threadIdx.x] - v;  // exclusive within block
    if (threadIdx.x == SCAN_B - 1) bsums[blockIdx.x] = buf[threadIdx.x];
}

// scan3 also computes its own block-prefix from bsums.
__global__ void scan3_kernel(int* __restrict__ rowptr, const int* __restrict__ bsums,
                             int* __restrict__ cursor, int n, int total) {
    __shared__ int base_s;
    if (threadIdx.x < 64) {
        int v = (threadIdx.x < (int)blockIdx.x) ? bsums[threadIdx.x] : 0;
        #pragma unroll
        for (int off = 32; off > 0; off >>= 1) v += __shfl_down(v, off, 64);
        if (threadIdx.x == 0) base_s = v;
    }
    __syncthreads();
    int base = base_s;
    int gid = blockIdx.x * SCAN_B + threadIdx.x;
    if (gid < n) {
        int v = rowptr[gid] + base;
        rowptr[gid] = v;
        cursor[gid] = v;
    }
    if (gid == 0) rowptr[n] = total;
}

__global__ void scatter_kernel(const int* __restrict__ ei, int* __restrict__ cursor,
                               int* __restrict__ adj) {
    int e = blockIdx.x * blockDim.x + threadIdx.x;
    if (e >= TOT_E) return;
    int s, d;
    if (e < N_EDGES) { s = ei[e]; d = ei[N_EDGES + e]; }
    else             { s = e - N_EDGES; d = s; }
    int pos = atomicAdd(&cursor[d], 1);
    adj[pos] = s;
}

// ---------------- precompute Wa = W @ a  (s = h@a == x@(W@a)) ----------------
__global__ void prep_wa(const float* __restrict__ W1, const float* __restrict__ a1s,
                        const float* __restrict__ a1d, const float* __restrict__ W2,
                        const float* __restrict__ a2s, const float* __restrict__ a2d,
                        float* __restrict__ wa) {
    int t = threadIdx.x;          // 512 threads, 1 block
    int vec = t >> 7, k = t & 127;
    const float* W = (vec < 2) ? W1 : W2;
    const float* a = (vec == 0) ? a1s : (vec == 1) ? a1d : (vec == 2) ? a2s : a2d;
    float s = 0.f;
    #pragma unroll 4
    for (int j = 0; j < FDIM; j += 4) {
        float4 wv = *(const float4*)&W[k * FDIM + j];
        float4 av = *(const float4*)&a[j];
        s += wv.x * av.x + wv.y * av.y + wv.z * av.z + wv.w * av.w;
    }
    wa[vec * FDIM + k] = s;
}

// ---------------- GEMM (h = X @ W) + fused attention scores ----------------
// 16 rows/block, 128 threads. Thread owns cols (c, c+64) x 8 rows (C=2 tile):
// halves ds_read_b128 issue per FMA vs col-per-thread.
#define GR 16
__global__ __launch_bounds__(128) void gemm_att_kernel(
        const float* __restrict__ X, const float* __restrict__ W,
        const float* __restrict__ wa_s, const float* __restrict__ wa_d,
        float* __restrict__ H, float* __restrict__ ssrc, float* __restrict__ sdst) {
    __shared__ float xs[GR][FDIM];
    int tid  = threadIdx.x;
    int row0 = blockIdx.x * GR;

    const float4* Xv = (const float4*)(X + (size_t)row0 * FDIM);
    float4* xsv = (float4*)&xs[0][0];
    #pragma unroll
    for (int i = 0; i < 4; i++) xsv[tid + 128 * i] = Xv[tid + 128 * i];
    __syncthreads();

    int c  = tid & 63;            // col pair (c, c+64)
    int rh = (tid >> 6) * 8;      // row half: wave0 rows 0..7, wave1 rows 8..15

    float2 acc[8];
    #pragma unroll
    for (int r = 0; r < 8; r++) acc[r] = make_float2(0.f, 0.f);

    #pragma unroll 2
    for (int k = 0; k < FDIM; k += 4) {
        float wl[4], wr[4];
        #pragma unroll
        for (int kk = 0; kk < 4; kk++) {
            wl[kk] = W[(k + kk) * FDIM + c];
            wr[kk] = W[(k + kk) * FDIM + c + 64];
        }
        #pragma unroll
        for (int r = 0; r < 8; r++) {
            float4 xv = *(const float4*)&xs[rh + r][k];   // LDS b128, 2-addr broadcast
            acc[r].x += xv.x * wl[0] + xv.y * wl[1] + xv.z * wl[2] + xv.w * wl[3];
            acc[r].y += xv.x * wr[0] + xv.y * wr[1] + xv.z * wr[2] + xv.w * wr[3];
        }
    }
    #pragma unroll
    for (int r = 0; r < 8; r++) {
        H[(size_t)(row0 + rh + r) * FDIM + c]      = acc[r].x;
        H[(size_t)(row0 + rh + r) * FDIM + c + 64] = acc[r].y;
    }

    // fused scores: slot = (row, src/dst), 4 lanes per slot
    int slot = tid >> 2, q = tid & 3;
    int r = slot >> 1;
    const float* av = (slot & 1) ? wa_d : wa_s;
    float p = 0.f;
    #pragma unroll
    for (int k = q * 32; k < q * 32 + 32; k += 4) {
        float4 xv = *(const float4*)&xs[r][k];
        p += xv.x * av[k] + xv.y * av[k + 1] + xv.z * av[k + 2] + xv.w * av[k + 3];
    }
    p += __shfl_down(p, 1, 4);
    p += __shfl_down(p, 2, 4);
    if (q == 0) { if (slot & 1) sdst[row0 + r] = p; else ssrc[row0 + r] = p; }
}

// ---------------- per-dst softmax + aggregation ----------------
// Wave-per-node, 2 nodes/block. No barriers, no max pass (softmax shift-invariant;
// |e| <= ~10 here so exp(e) is f32-safe). Per 64-edge chunk: 1 lane computes
// one edge's weight into per-wave LDS strip, then all 64 lanes sweep edges
// 4-at-a-time with float2 h-row loads (4 rows in flight, dual accumulators).
__global__ __launch_bounds__(128) void gat_aggregate(
        const float* __restrict__ h, const float* __restrict__ ssrc,
        const float* __restrict__ sdst, const int* __restrict__ rowptr,
        const int* __restrict__ adj, const float* __restrict__ bias,
        float* __restrict__ out, int do_relu) {
    int wv = threadIdx.x >> 6, lane = threadIdx.x & 63;
    int n = blockIdx.x * 2 + wv;
    __shared__ float wbuf[2][64];
    __shared__ int   sbuf[2][64];

    int beg = rowptr[n], deg = rowptr[n + 1] - beg;   // >= 1 (self loop)
    float sd = sdst[n];
    const float2* hv = (const float2*)h;

    float2 acc0 = make_float2(0.f, 0.f), acc1 = make_float2(0.f, 0.f);
    float dsum = 0.f;

    for (int base = 0; base < deg; base += 64) {
        int c = min(64, deg - base);
        if (lane < c) {
            int s = adj[beg + base + lane];
            float e = ssrc[s] + sd;
            e = (e >= 0.f) ? e : 0.2f * e;
            float w = __expf(e);
            wbuf[wv][lane] = w;
            sbuf[wv][lane] = s;
            dsum += w;
        }
        // wave-synchronous LDS: in-order DS pipe; stop compiler reordering and
        // drain ds_writes before cross-lane reads.
        asm volatile("s_waitcnt lgkmcnt(0)" ::: "memory");

        int j = 0;
        for (; j + 4 <= c; j += 4) {
            float4 w4 = *(const float4*)&wbuf[wv][j];   // uniform-addr broadcast
            int4   s4 = *(const int4*)&sbuf[wv][j];
            float2 h0 = hv[(size_t)s4.x * (FDIM / 2) + lane];
            float2 h1 = hv[(size_t)s4.y * (FDIM / 2) + lane];
            float2 h2 = hv[(size_t)s4.z * (FDIM / 2) + lane];
            float2 h3 = hv[(size_t)s4.w * (FDIM / 2) + lane];
            acc0.x += w4.x * h0.x; acc0.y += w4.x * h0.y;
            acc1.x += w4.y * h1.x; acc1.y += w4.y * h1.y;
            acc0.x += w4.z * h2.x; acc0.y += w4.z * h2.y;
            acc1.x += w4.w * h3.x; acc1.y += w4.w * h3.y;
        }
        for (; j < c; j++) {
            float w = wbuf[wv][j];
            int   s = sbuf[wv][j];
            float2 hx = hv[(size_t)s * (FDIM / 2) + lane];
            acc0.x += w * hx.x; acc0.y += w * hx.y;
        }
        asm volatile("" ::: "memory");   // keep chunk phases ordered
    }

    #pragma unroll
    for (int off = 32; off > 0; off >>= 1) dsum += __shfl_xor(dsum, off, 64);
    float inv = 1.f / dsum;
    float2 b2 = ((const float2*)bias)[lane];
    float vx = (acc0.x + acc1.x) * inv + b2.x;
    float vy = (acc0.y + acc1.y) * inv + b2.y;
    if (do_relu) { vx = fmaxf(vx, 0.f); vy = fmaxf(vy, 0.f); }
    ((float2*)out)[(size_t)n * (FDIM / 2) + lane] = make_float2(vx, vy);
}

// ---------------- classifier: log_softmax(H @ Wl + bl), 16 rows/block ----------------
__global__ __launch_bounds__(128) void classifier_kernel(
        const float* __restrict__ H, const float* __restrict__ Wl,
        const float* __restrict__ bl, float* __restrict__ out) {
    __shared__ float xs[16][FDIM];
    int tid  = threadIdx.x;
    int row0 = blockIdx.x * 16;
    const float4* Hv = (const float4*)(H + (size_t)row0 * FDIM);
    float4* xsv = (float4*)&xs[0][0];
    #pragma unroll
    for (int i = 0; i < 4; i++) xsv[tid + 128 * i] = Hv[tid + 128 * i];
    __syncthreads();

    int c = tid & 63, hw = tid >> 6;    // wave hw handles rows hw*8 .. hw*8+7
    float acc[8];
    float blc = (c < NCLS) ? bl[c] : 0.f;
    #pragma unroll
    for (int r = 0; r < 8; r++) acc[r] = blc;

    #pragma unroll 2
    for (int k = 0; k < FDIM; k += 4) {
        float w0 = 0.f, w1 = 0.f, w2 = 0.f, w3 = 0.f;
        if (c < NCLS) {
            w0 = Wl[(k + 0) * NCLS + c]; w1 = Wl[(k + 1) * NCLS + c];
            w2 = Wl[(k + 2) * NCLS + c]; w3 = Wl[(k + 3) * NCLS + c];
        }
        #pragma unroll
        for (int r = 0; r < 8; r++) {
            float4 xv = *(const float4*)&xs[hw * 8 + r][k];
            acc[r] += xv.x * w0 + xv.y * w1 + xv.z * w2 + xv.w * w3;
        }
    }
    #pragma unroll
    for (int r = 0; r < 8; r++) {
        float v = (c < NCLS) ? acc[r] : -INFINITY;
        float mx = v;
        #pragma unroll
        for (int off = 32; off > 0; off >>= 1) mx = fmaxf(mx, __shfl_xor(mx, off, 64));
        float ex = (c < NCLS) ? expf(v - mx) : 0.f;
        #pragma unroll
        for (int off = 32; off > 0; off >>= 1) ex += __shfl_xor(ex, off, 64);
        float ls = logf(ex);
        if (c < NCLS) out[(size_t)(row0 + hw * 8 + r) * NCLS + c] = v - mx - ls;
    }
}

// ---------------- edge_index pass-through (as f32), vectorized ----------------
__global__ void edge_copy_kernel(const int* __restrict__ ei, float* __restrict__ out) {
    int i = blockIdx.x * blockDim.x + threadIdx.x;
    if (i >= (2 * N_EDGES) / 4) return;
    int4 v = ((const int4*)ei)[i];
    float4 f = make_float4((float)v.x, (float)v.y, (float)v.z, (float)v.w);
    ((float4*)out)[i] = f;
}

extern "C" void kernel_launch(void* const* d_in, const int* in_sizes, int n_in,
                              void* d_out, int out_size, void* d_ws, size_t ws_size,
                              hipStream_t stream) {
    const float* x   = (const float*)d_in[0];
    const int*   ei  = (const int*)d_in[1];
    const float* W1  = (const float*)d_in[2];
    const float* a1s = (const float*)d_in[3];
    const float* a1d = (const float*)d_in[4];
    const float* b1  = (const float*)d_in[5];
    const float* W2  = (const float*)d_in[6];
    const float* a2s = (const float*)d_in[7];
    const float* a2d = (const float*)d_in[8];
    const float* b2  = (const float*)d_in[9];
    const float* Wl  = (const float*)d_in[10];
    const float* bl  = (const float*)d_in[11];
    float* out = (float*)d_out;

    char* ws = (char*)d_ws;
    size_t off = 0;
    auto alloc = [&](size_t bytes) {
        void* p = ws + off;
        off = (off + bytes + 255) & ~(size_t)255;
        return p;
    };
    int*   row_ptr = (int*)alloc((N_NODES + 1) * sizeof(int));
    int*   cursor  = (int*)alloc(N_NODES * sizeof(int));
    int*   counts  = (int*)alloc(N_NODES * sizeof(int));
    int*   bsums   = (int*)alloc(64 * sizeof(int));
    int*   adj     = (int*)alloc(TOT_E * sizeof(int));
    float* hA      = (float*)alloc((size_t)N_NODES * FDIM * sizeof(float));
    float* hB      = (float*)alloc((size_t)N_NODES * FDIM * sizeof(float));
    float* ssrc    = (float*)alloc(N_NODES * sizeof(float));
    float* sdst    = (float*)alloc(N_NODES * sizeof(float));
    float* wa      = (float*)alloc(4 * FDIM * sizeof(float));

    // ---- Wa precompute (independent) ----
    hipLaunchKernelGGL(prep_wa, dim3(1), dim3(512), 0, stream, W1, a1s, a1d, W2, a2s, a2d, wa);

    // ---- CSR build ----
    hipMemsetAsync(counts, 0, N_NODES * sizeof(int), stream);
    {
        int thr = 256, grid = (TOT_E + thr - 1) / thr;
        hipLaunchKernelGGL(hist_kernel, dim3(grid), dim3(thr), 0, stream, ei, counts);
    }
    int nscan = (N_NODES + SCAN_B - 1) / SCAN_B;  // 49
    hipLaunchKernelGGL(scan1_kernel, dim3(nscan), dim3(SCAN_B), 0, stream, counts, row_ptr, bsums, N_NODES);
    hipLaunchKernelGGL(scan3_kernel, dim3(nscan), dim3(SCAN_B), 0, stream, row_ptr, bsums, cursor, N_NODES, TOT_E);
    {
        int thr = 256, grid = (TOT_E + thr - 1) / thr;
        hipLaunchKernelGGL(scatter_kernel, dim3(grid), dim3(thr), 0, stream, ei, cursor, adj);
    }

    // ---- layer 1 ----
    hipLaunchKernelGGL(gemm_att_kernel, dim3(N_NODES / GR), dim3(128), 0, stream,
                       x, W1, wa + 0, wa + FDIM, hA, ssrc, sdst);
    hipLaunchKernelGGL(gat_aggregate, dim3(N_NODES / 2), dim3(128), 0, stream,
                       hA, ssrc, sdst, row_ptr, adj, b1, hB, 1);

    // ---- layer 2 ----
    hipLaunchKernelGGL(gemm_att_kernel, dim3(N_NODES / GR), dim3(128), 0, stream,
                       hB, W2, wa + 2 * FDIM, wa + 3 * FDIM, hA, ssrc, sdst);
    hipLaunchKernelGGL(gat_aggregate, dim3(N_NODES / 2), dim3(128), 0, stream,
                       hA, ssrc, sdst, row_ptr, adj, b2, hB, 0);

    // ---- classifier + edge pass-through ----
    hipLaunchKernelGGL(classifier_kernel, dim3(N_NODES / 16), dim3(128), 0, stream, hB, Wl, bl, out);
    {
        int thr = 256, grid = ((2 * N_EDGES) / 4 + thr - 1) / thr;
        hipLaunchKernelGGL(edge_copy_kernel, dim3(grid), dim3(thr), 0, stream,
                           ei, out + (size_t)N_NODES * NCLS);
    }
}

// Round 4
// 333.319 us; speedup vs baseline: 1.3542x; 1.1284x over previous
//
#include <hip/hip_runtime.h>
#include <hip/hip_bf16.h>
#include <math.h>

#define N_NODES 50000
#define N_EDGES 600000
#define TOT_E   (N_EDGES + N_NODES)   // with self loops
#define FDIM    128
#define HROW    64                    // packed bf16 row: 64 uint32 = 128 bf16
#define NCLS    40
#define SCAN_B  1024

// ---------------- bf16 pack/unpack (RNE) ----------------
__device__ inline float bf16_lo(uint32_t u) { return __uint_as_float(u << 16); }
__device__ inline float bf16_hi(uint32_t u) { return __uint_as_float(u & 0xffff0000u); }
__device__ inline uint32_t bf16_pack(float a, float b) {
    uint32_t ua = __float_as_uint(a), ub = __float_as_uint(b);
    uint32_t ra = (ua + 0x7fffu + ((ua >> 16) & 1u)) >> 16;
    uint32_t rb = (ub + 0x7fffu + ((ub >> 16) & 1u)) >> 16;
    return ra | (rb << 16);
}

// ---------------- CSR build ----------------
__global__ void init_counts(int* __restrict__ counts) {
    int i = blockIdx.x * blockDim.x + threadIdx.x;
    if (i < N_NODES) counts[i] = 1;          // self loop pre-counted
}

__global__ void hist_kernel(const int* __restrict__ ei, int* __restrict__ counts) {
    int i = blockIdx.x * blockDim.x + threadIdx.x;
    if (i >= N_EDGES / 4) return;
    int4 d = ((const int4*)(ei + N_EDGES))[i];
    atomicAdd(&counts[d.x], 1);
    atomicAdd(&counts[d.y], 1);
    atomicAdd(&counts[d.z], 1);
    atomicAdd(&counts[d.w], 1);
}

// shfl-based block scan: 2 barriers instead of 40.
__global__ void scan1_kernel(const int* __restrict__ counts, int* __restrict__ excl,
                             int* __restrict__ bsums, int n) {
    __shared__ int ws[16];
    int gid = blockIdx.x * SCAN_B + threadIdx.x;
    int wv = threadIdx.x >> 6, lane = threadIdx.x & 63;
    int v = (gid < n) ? counts[gid] : 0;
    int incl = v;
    #pragma unroll
    for (int off = 1; off < 64; off <<= 1) {
        int t = __shfl_up(incl, off, 64);
        if (lane >= off) incl += t;
    }
    if (lane == 63) ws[wv] = incl;
    __syncthreads();
    int woff = 0;
    for (int i = 0; i < wv; i++) woff += ws[i];   // wave-uniform, LDS broadcast
    if (gid < n) excl[gid] = woff + incl - v;
    if (threadIdx.x == SCAN_B - 1) bsums[blockIdx.x] = woff + incl;
}

__global__ void scan3_kernel(int* __restrict__ rowptr, const int* __restrict__ bsums,
                             int* __restrict__ cursor, int n, int total) {
    __shared__ int base_s;
    if (threadIdx.x < 64) {
        int v = (threadIdx.x < (int)blockIdx.x) ? bsums[threadIdx.x] : 0;
        #pragma unroll
        for (int off = 32; off > 0; off >>= 1) v += __shfl_down(v, off, 64);
        if (threadIdx.x == 0) base_s = v;
    }
    __syncthreads();
    int base = base_s;
    int gid = blockIdx.x * SCAN_B + threadIdx.x;
    if (gid < n) {
        int v = rowptr[gid] + base;
        rowptr[gid] = v;
        cursor[gid] = v;
    }
    if (gid == 0) rowptr[n] = total;
}

#define SCAT_T ((N_EDGES / 4) + N_NODES)
__global__ void scatter_kernel(const int* __restrict__ ei, int* __restrict__ cursor,
                               int* __restrict__ adj) {
    int i = blockIdx.x * blockDim.x + threadIdx.x;
    if (i >= SCAT_T) return;
    if (i < N_EDGES / 4) {
        int4 s4 = ((const int4*)ei)[i];
        int4 d4 = ((const int4*)(ei + N_EDGES))[i];
        adj[atomicAdd(&cursor[d4.x], 1)] = s4.x;
        adj[atomicAdd(&cursor[d4.y], 1)] = s4.y;
        adj[atomicAdd(&cursor[d4.z], 1)] = s4.z;
        adj[atomicAdd(&cursor[d4.w], 1)] = s4.w;
    } else {
        int nd = i - N_EDGES / 4;
        adj[atomicAdd(&cursor[nd], 1)] = nd;
    }
}

// ---------------- precompute Wa = W @ a  (s = h@a == x@(W@a)) ----------------
__global__ void prep_wa(const float* __restrict__ W1, const float* __restrict__ a1s,
                        const float* __restrict__ a1d, const float* __restrict__ W2,
                        const float* __restrict__ a2s, const float* __restrict__ a2d,
                        float* __restrict__ wa) {
    int t = threadIdx.x;          // 512 threads, 1 block
    int vec = t >> 7, k = t & 127;
    const float* W = (vec < 2) ? W1 : W2;
    const float* a = (vec == 0) ? a1s : (vec == 1) ? a1d : (vec == 2) ? a2s : a2d;
    float s = 0.f;
    #pragma unroll 4
    for (int j = 0; j < FDIM; j += 4) {
        float4 wv = *(const float4*)&W[k * FDIM + j];
        float4 av = *(const float4*)&a[j];
        s += wv.x * av.x + wv.y * av.y + wv.z * av.z + wv.w * av.w;
    }
    wa[vec * FDIM + k] = s;
}

// ---------------- GEMM (h = X @ W) + fused attention scores ----------------
// 16 rows/block, 128 threads. Thread owns adjacent cols (2c, 2c+1) x 8 rows,
// so the two outputs pack into one bf16 dword. W loads are coalesced float2.
#define GR 16
template <bool BF16IN>
__global__ __launch_bounds__(128) void gemm_att_kernel(
        const void* __restrict__ Xin, const float* __restrict__ W,
        const float* __restrict__ wa_s, const float* __restrict__ wa_d,
        uint32_t* __restrict__ H, float* __restrict__ ssrc, float* __restrict__ sdst) {
    __shared__ float xs[GR][FDIM];
    int tid  = threadIdx.x;
    int row0 = blockIdx.x * GR;

    if (BF16IN) {
        const uint32_t* Xp = (const uint32_t*)Xin + (size_t)row0 * HROW;
        #pragma unroll
        for (int i = 0; i < 8; i++) {           // 16 rows x 64 dwords = 1024
            int idx = tid + 128 * i;
            uint32_t u = Xp[idx];
            int r = idx >> 6, cc = idx & 63;
            xs[r][2 * cc]     = bf16_lo(u);
            xs[r][2 * cc + 1] = bf16_hi(u);
        }
    } else {
        const float4* Xv = (const float4*)((const float*)Xin + (size_t)row0 * FDIM);
        float4* xsv = (float4*)&xs[0][0];
        #pragma unroll
        for (int i = 0; i < 4; i++) xsv[tid + 128 * i] = Xv[tid + 128 * i];
    }
    __syncthreads();

    int c  = tid & 63;            // output col pair (2c, 2c+1)
    int rh = (tid >> 6) * 8;      // wave0 rows 0..7, wave1 rows 8..15

    float2 acc[8];
    #pragma unroll
    for (int r = 0; r < 8; r++) acc[r] = make_float2(0.f, 0.f);

    #pragma unroll 2
    for (int k = 0; k < FDIM; k += 4) {
        float2 w01[4];
        #pragma unroll
        for (int kk = 0; kk < 4; kk++)
            w01[kk] = *(const float2*)&W[(k + kk) * FDIM + 2 * c];
        #pragma unroll
        for (int r = 0; r < 8; r++) {
            float4 xv = *(const float4*)&xs[rh + r][k];   // LDS b128 broadcast
            acc[r].x += xv.x * w01[0].x + xv.y * w01[1].x + xv.z * w01[2].x + xv.w * w01[3].x;
            acc[r].y += xv.x * w01[0].y + xv.y * w01[1].y + xv.z * w01[2].y + xv.w * w01[3].y;
        }
    }
    #pragma unroll
    for (int r = 0; r < 8; r++)
        H[(size_t)(row0 + rh + r) * HROW + c] = bf16_pack(acc[r].x, acc[r].y);

    // fused scores: slot = (row, src/dst), 4 lanes per slot
    int slot = tid >> 2, q = tid & 3;
    int r = slot >> 1;
    const float* av = (slot & 1) ? wa_d : wa_s;
    float p = 0.f;
    #pragma unroll
    for (int k = q * 32; k < q * 32 + 32; k += 4) {
        float4 xv = *(const float4*)&xs[r][k];
        p += xv.x * av[k] + xv.y * av[k + 1] + xv.z * av[k + 2] + xv.w * av[k + 3];
    }
    p += __shfl_down(p, 1, 4);
    p += __shfl_down(p, 2, 4);
    if (q == 0) { if (slot & 1) sdst[row0 + r] = p; else ssrc[row0 + r] = p; }
}

// ---------------- per-dst softmax + aggregation (bf16 rows) ----------------
// Wave-per-node, 2 nodes/block, barrier-free. 8 edges unrolled -> 8 dword
// row-loads in flight per lane. No max pass (softmax shift-invariant, |e|<~10).
__global__ __launch_bounds__(128) void gat_aggregate(
        const uint32_t* __restrict__ h, const float* __restrict__ ssrc,
        const float* __restrict__ sdst, const int* __restrict__ rowptr,
        const int* __restrict__ adj, const float* __restrict__ bias,
        uint32_t* __restrict__ out, int do_relu) {
    int wv = threadIdx.x >> 6, lane = threadIdx.x & 63;
    int n = blockIdx.x * 2 + wv;
    __shared__ __align__(16) float wbuf[2][64];
    __shared__ __align__(16) int   sbuf[2][64];

    int beg = rowptr[n], deg = rowptr[n + 1] - beg;   // >= 1 (self loop)
    float sd = sdst[n];

    float ax0 = 0.f, ay0 = 0.f, ax1 = 0.f, ay1 = 0.f;
    float dsum = 0.f;

    for (int base = 0; base < deg; base += 64) {
        int c = min(64, deg - base);
        if (lane < c) {
            int s = adj[beg + base + lane];
            float e = ssrc[s] + sd;
            e = (e >= 0.f) ? e : 0.2f * e;
            float w = __expf(e);
            wbuf[wv][lane] = w;
            sbuf[wv][lane] = s;
            dsum += w;
        }
        // wave-synchronous LDS: drain ds_writes before cross-lane reads.
        asm volatile("s_waitcnt lgkmcnt(0)" ::: "memory");

        int j = 0;
        for (; j + 8 <= c; j += 8) {
            float4 wa4 = *(const float4*)&wbuf[wv][j];
            float4 wb4 = *(const float4*)&wbuf[wv][j + 4];
            int4   sa4 = *(const int4*)&sbuf[wv][j];
            int4   sb4 = *(const int4*)&sbuf[wv][j + 4];
            uint32_t u0 = h[(size_t)sa4.x * HROW + lane];
            uint32_t u1 = h[(size_t)sa4.y * HROW + lane];
            uint32_t u2 = h[(size_t)sa4.z * HROW + lane];
            uint32_t u3 = h[(size_t)sa4.w * HROW + lane];
            uint32_t u4 = h[(size_t)sb4.x * HROW + lane];
            uint32_t u5 = h[(size_t)sb4.y * HROW + lane];
            uint32_t u6 = h[(size_t)sb4.z * HROW + lane];
            uint32_t u7 = h[(size_t)sb4.w * HROW + lane];
            ax0 += wa4.x * bf16_lo(u0); ay0 += wa4.x * bf16_hi(u0);
            ax1 += wa4.y * bf16_lo(u1); ay1 += wa4.y * bf16_hi(u1);
            ax0 += wa4.z * bf16_lo(u2); ay0 += wa4.z * bf16_hi(u2);
            ax1 += wa4.w * bf16_lo(u3); ay1 += wa4.w * bf16_hi(u3);
            ax0 += wb4.x * bf16_lo(u4); ay0 += wb4.x * bf16_hi(u4);
            ax1 += wb4.y * bf16_lo(u5); ay1 += wb4.y * bf16_hi(u5);
            ax0 += wb4.z * bf16_lo(u6); ay0 += wb4.z * bf16_hi(u6);
            ax1 += wb4.w * bf16_lo(u7); ay1 += wb4.w * bf16_hi(u7);
        }
        for (; j + 4 <= c; j += 4) {
            float4 w4 = *(const float4*)&wbuf[wv][j];
            int4   s4 = *(const int4*)&sbuf[wv][j];
            uint32_t u0 = h[(size_t)s4.x * HROW + lane];
            uint32_t u1 = h[(size_t)s4.y * HROW + lane];
            uint32_t u2 = h[(size_t)s4.z * HROW + lane];
            uint32_t u3 = h[(size_t)s4.w * HROW + lane];
            ax0 += w4.x * bf16_lo(u0); ay0 += w4.x * bf16_hi(u0);
            ax1 += w4.y * bf16_lo(u1); ay1 += w4.y * bf16_hi(u1);
            ax0 += w4.z * bf16_lo(u2); ay0 += w4.z * bf16_hi(u2);
            ax1 += w4.w * bf16_lo(u3); ay1 += w4.w * bf16_hi(u3);
        }
        for (; j < c; j++) {
            float w = wbuf[wv][j];
            int   s = sbuf[wv][j];
            uint32_t u = h[(size_t)s * HROW + lane];
            ax0 += w * bf16_lo(u); ay0 += w * bf16_hi(u);
        }
        asm volatile("" ::: "memory");   // keep chunk phases ordered
    }

    #pragma unroll
    for (int off = 32; off > 0; off >>= 1) dsum += __shfl_xor(dsum, off, 64);
    float inv = 1.f / dsum;
    float2 b2 = ((const float2*)bias)[lane];
    float vx = (ax0 + ax1) * inv + b2.x;
    float vy = (ay0 + ay1) * inv + b2.y;
    if (do_relu) { vx = fmaxf(vx, 0.f); vy = fmaxf(vy, 0.f); }
    out[(size_t)n * HROW + lane] = bf16_pack(vx, vy);
}

// ---------------- classifier: log_softmax(H @ Wl + bl), bf16 in ----------------
__global__ __launch_bounds__(128) void classifier_kernel(
        const uint32_t* __restrict__ H, const float* __restrict__ Wl,
        const float* __restrict__ bl, float* __restrict__ out) {
    __shared__ float xs[16][FDIM];
    int tid  = threadIdx.x;
    int row0 = blockIdx.x * 16;
    const uint32_t* Hp = H + (size_t)row0 * HROW;
    #pragma unroll
    for (int i = 0; i < 8; i++) {
        int idx = tid + 128 * i;
        uint32_t u = Hp[idx];
        int r = idx >> 6, cc = idx & 63;
        xs[r][2 * cc]     = bf16_lo(u);
        xs[r][2 * cc + 1] = bf16_hi(u);
    }
    __syncthreads();

    int c = tid & 63, hw = tid >> 6;    // wave hw handles rows hw*8 .. hw*8+7
    float acc[8];
    float blc = (c < NCLS) ? bl[c] : 0.f;
    #pragma unroll
    for (int r = 0; r < 8; r++) acc[r] = blc;

    #pragma unroll 2
    for (int k = 0; k < FDIM; k += 4) {
        float w0 = 0.f, w1 = 0.f, w2 = 0.f, w3 = 0.f;
        if (c < NCLS) {
            w0 = Wl[(k + 0) * NCLS + c]; w1 = Wl[(k + 1) * NCLS + c];
            w2 = Wl[(k + 2) * NCLS + c]; w3 = Wl[(k + 3) * NCLS + c];
        }
        #pragma unroll
        for (int r = 0; r < 8; r++) {
            float4 xv = *(const float4*)&xs[hw * 8 + r][k];
            acc[r] += xv.x * w0 + xv.y * w1 + xv.z * w2 + xv.w * w3;
        }
    }
    #pragma unroll
    for (int r = 0; r < 8; r++) {
        float v = (c < NCLS) ? acc[r] : -INFINITY;
        float mx = v;
        #pragma unroll
        for (int off = 32; off > 0; off >>= 1) mx = fmaxf(mx, __shfl_xor(mx, off, 64));
        float ex = (c < NCLS) ? expf(v - mx) : 0.f;
        #pragma unroll
        for (int off = 32; off > 0; off >>= 1) ex += __shfl_xor(ex, off, 64);
        float ls = logf(ex);
        if (c < NCLS) out[(size_t)(row0 + hw * 8 + r) * NCLS + c] = v - mx - ls;
    }
}

// ---------------- edge_index pass-through (as f32), vectorized ----------------
__global__ void edge_copy_kernel(const int* __restrict__ ei, float* __restrict__ out) {
    int i = blockIdx.x * blockDim.x + threadIdx.x;
    if (i >= (2 * N_EDGES) / 4) return;
    int4 v = ((const int4*)ei)[i];
    ((float4*)out)[i] = make_float4((float)v.x, (float)v.y, (float)v.z, (float)v.w);
}

extern "C" void kernel_launch(void* const* d_in, const int* in_sizes, int n_in,
                              void* d_out, int out_size, void* d_ws, size_t ws_size,
                              hipStream_t stream) {
    const float* x   = (const float*)d_in[0];
    const int*   ei  = (const int*)d_in[1];
    const float* W1  = (const float*)d_in[2];
    const float* a1s = (const float*)d_in[3];
    const float* a1d = (const float*)d_in[4];
    const float* b1  = (const float*)d_in[5];
    const float* W2  = (const float*)d_in[6];
    const float* a2s = (const float*)d_in[7];
    const float* a2d = (const float*)d_in[8];
    const float* b2  = (const float*)d_in[9];
    const float* Wl  = (const float*)d_in[10];
    const float* bl  = (const float*)d_in[11];
    float* out = (float*)d_out;

    char* ws = (char*)d_ws;
    size_t off = 0;
    auto alloc = [&](size_t bytes) {
        void* p = ws + off;
        off = (off + bytes + 255) & ~(size_t)255;
        return p;
    };
    int*      row_ptr = (int*)alloc((N_NODES + 1) * sizeof(int));
    int*      cursor  = (int*)alloc(N_NODES * sizeof(int));
    int*      counts  = (int*)alloc(N_NODES * sizeof(int));
    int*      bsums   = (int*)alloc(64 * sizeof(int));
    int*      adj     = (int*)alloc(TOT_E * sizeof(int));
    uint32_t* hA      = (uint32_t*)alloc((size_t)N_NODES * HROW * sizeof(uint32_t));
    uint32_t* hB      = (uint32_t*)alloc((size_t)N_NODES * HROW * sizeof(uint32_t));
    float*    ssrc    = (float*)alloc(N_NODES * sizeof(float));
    float*    sdst    = (float*)alloc(N_NODES * sizeof(float));
    float*    wa      = (float*)alloc(4 * FDIM * sizeof(float));

    // ---- Wa precompute ----
    hipLaunchKernelGGL(prep_wa, dim3(1), dim3(512), 0, stream, W1, a1s, a1d, W2, a2s, a2d, wa);

    // ---- CSR build ----
    hipLaunchKernelGGL(init_counts, dim3((N_NODES + 255) / 256), dim3(256), 0, stream, counts);
    hipLaunchKernelGGL(hist_kernel, dim3((N_EDGES / 4 + 255) / 256), dim3(256), 0, stream, ei, counts);
    int nscan = (N_NODES + SCAN_B - 1) / SCAN_B;  // 49
    hipLaunchKernelGGL(scan1_kernel, dim3(nscan), dim3(SCAN_B), 0, stream, counts, row_ptr, bsums, N_NODES);
    hipLaunchKernelGGL(scan3_kernel, dim3(nscan), dim3(SCAN_B), 0, stream, row_ptr, bsums, cursor, N_NODES, TOT_E);
    hipLaunchKernelGGL(scatter_kernel, dim3((SCAT_T + 255) / 256), dim3(256), 0, stream, ei, cursor, adj);

    // ---- layer 1 ----
    hipLaunchKernelGGL((gemm_att_kernel<false>), dim3(N_NODES / GR), dim3(128), 0, stream,
                       (const void*)x, W1, wa + 0, wa + FDIM, hA, ssrc, sdst);
    hipLaunchKernelGGL(gat_aggregate, dim3(N_NODES / 2), dim3(128), 0, stream,
                       hA, ssrc, sdst, row_ptr, adj, b1, hB, 1);

    // ---- layer 2 ----
    hipLaunchKernelGGL((gemm_att_kernel<true>), dim3(N_NODES / GR), dim3(128), 0, stream,
                       (const void*)hB, W2, wa + 2 * FDIM, wa + 3 * FDIM, hA, ssrc, sdst);
    hipLaunchKernelGGL(gat_aggregate, dim3(N_NODES / 2), dim3(128), 0, stream,
                       hA, ssrc, sdst, row_ptr, adj, b2, hB, 0);

    // ---- classifier + edge pass-through ----
    hipLaunchKernelGGL(classifier_kernel, dim3(N_NODES / 16), dim3(128), 0, stream, hB, Wl, bl, out);
    hipLaunchKernelGGL(edge_copy_kernel, dim3(((2 * N_EDGES) / 4 + 255) / 256), dim3(256), 0, stream,
                       ei, out + (size_t)N_NODES * NCLS);
}

// Round 5
// 311.612 us; speedup vs baseline: 1.4486x; 1.0697x over previous
//
#include <hip/hip_runtime.h>
#include <hip/hip_bf16.h>
#include <math.h>

#define N_NODES 50000
#define N_EDGES 600000
#define TOT_E   (N_EDGES + N_NODES)   // with self loops
#define FDIM    128
#define HROW    64                    // packed bf16 row: 64 uint32 = 128 bf16
#define NCLS    40
#define SCAN_B  1024

typedef __attribute__((ext_vector_type(4))) float  f32x4;
typedef __attribute__((ext_vector_type(8))) __bf16 bf16x8;
union FragU { uint32_t u[4]; bf16x8 v; };

// ---------------- bf16 pack/unpack (RNE) ----------------
__device__ inline float bf16_lo(uint32_t u) { return __uint_as_float(u << 16); }
__device__ inline float bf16_hi(uint32_t u) { return __uint_as_float(u & 0xffff0000u); }
__device__ inline uint32_t bf16_pack(float a, float b) {
    uint32_t ua = __float_as_uint(a), ub = __float_as_uint(b);
    uint32_t ra = (ua + 0x7fffu + ((ua >> 16) & 1u)) >> 16;
    uint32_t rb = (ub + 0x7fffu + ((ub >> 16) & 1u)) >> 16;
    return ra | (rb << 16);
}

// ---------------- CSR build ----------------
__global__ void init_counts(int* __restrict__ counts) {
    int i = blockIdx.x * blockDim.x + threadIdx.x;
    if (i < N_NODES) counts[i] = 1;          // self loop pre-counted
}

__global__ void hist_kernel(const int* __restrict__ ei, int* __restrict__ counts) {
    int i = blockIdx.x * blockDim.x + threadIdx.x;
    if (i >= N_EDGES / 4) return;
    int4 d = ((const int4*)(ei + N_EDGES))[i];
    atomicAdd(&counts[d.x], 1);
    atomicAdd(&counts[d.y], 1);
    atomicAdd(&counts[d.z], 1);
    atomicAdd(&counts[d.w], 1);
}

// shfl-based block scan
__global__ void scan1_kernel(const int* __restrict__ counts, int* __restrict__ excl,
                             int* __restrict__ bsums, int n) {
    __shared__ int ws[16];
    int gid = blockIdx.x * SCAN_B + threadIdx.x;
    int wv = threadIdx.x >> 6, lane = threadIdx.x & 63;
    int v = (gid < n) ? counts[gid] : 0;
    int incl = v;
    #pragma unroll
    for (int off = 1; off < 64; off <<= 1) {
        int t = __shfl_up(incl, off, 64);
        if (lane >= off) incl += t;
    }
    if (lane == 63) ws[wv] = incl;
    __syncthreads();
    int woff = 0;
    for (int i = 0; i < wv; i++) woff += ws[i];
    if (gid < n) excl[gid] = woff + incl - v;
    if (threadIdx.x == SCAN_B - 1) bsums[blockIdx.x] = woff + incl;
}

__global__ void scan3_kernel(int* __restrict__ rowptr, const int* __restrict__ bsums,
                             int* __restrict__ cursor, int n, int total) {
    __shared__ int base_s;
    if (threadIdx.x < 64) {
        int v = (threadIdx.x < (int)blockIdx.x) ? bsums[threadIdx.x] : 0;
        #pragma unroll
        for (int off = 32; off > 0; off >>= 1) v += __shfl_down(v, off, 64);
        if (threadIdx.x == 0) base_s = v;
    }
    __syncthreads();
    int base = base_s;
    int gid = blockIdx.x * SCAN_B + threadIdx.x;
    if (gid < n) {
        int v = rowptr[gid] + base;
        rowptr[gid] = v;
        cursor[gid] = v;
    }
    if (gid == 0) rowptr[n] = total;
}

#define SCAT_T ((N_EDGES / 4) + N_NODES)
__global__ void scatter_kernel(const int* __restrict__ ei, int* __restrict__ cursor,
                               int* __restrict__ adj) {
    int i = blockIdx.x * blockDim.x + threadIdx.x;
    if (i >= SCAT_T) return;
    if (i < N_EDGES / 4) {
        int4 s4 = ((const int4*)ei)[i];
        int4 d4 = ((const int4*)(ei + N_EDGES))[i];
        adj[atomicAdd(&cursor[d4.x], 1)] = s4.x;
        adj[atomicAdd(&cursor[d4.y], 1)] = s4.y;
        adj[atomicAdd(&cursor[d4.z], 1)] = s4.z;
        adj[atomicAdd(&cursor[d4.w], 1)] = s4.w;
    } else {
        int nd = i - N_EDGES / 4;
        adj[atomicAdd(&cursor[nd], 1)] = nd;
    }
}

// ---------------- precompute Wa = W @ a ----------------
__global__ void prep_wa(const float* __restrict__ W1, const float* __restrict__ a1s,
                        const float* __restrict__ a1d, const float* __restrict__ W2,
                        const float* __restrict__ a2s, const float* __restrict__ a2d,
                        float* __restrict__ wa) {
    int t = threadIdx.x;          // 512 threads, 1 block
    int vec = t >> 7, k = t & 127;
    const float* W = (vec < 2) ? W1 : W2;
    const float* a = (vec == 0) ? a1s : (vec == 1) ? a1d : (vec == 2) ? a2s : a2d;
    float s = 0.f;
    #pragma unroll 4
    for (int j = 0; j < FDIM; j += 4) {
        float4 wv = *(const float4*)&W[k * FDIM + j];
        float4 av = *(const float4*)&a[j];
        s += wv.x * av.x + wv.y * av.y + wv.z * av.z + wv.w * av.w;
    }
    wa[vec * FDIM + k] = s;
}

// ---------------- pack x (f32 -> bf16 dwords) ----------------
__global__ void pack_x(const float* __restrict__ x, uint32_t* __restrict__ Xp) {
    int i = blockIdx.x * blockDim.x + threadIdx.x;    // dword index
    if (i >= N_NODES * HROW) return;
    float2 v = ((const float2*)x)[i];
    Xp[i] = bf16_pack(v.x, v.y);
}

// ---------------- prepack W into MFMA B-fragment order ----------------
// frag index (kt, nt, lane): lane holds W[k][n], n = nt*16 + (lane&15),
// k = kt*32 + 4*(lane>>4) + (e&3) + 16*(e>>2); dword d packs e=2d,2d+1.
__global__ void prep_wfrag(const float* __restrict__ W1, const float* __restrict__ W2,
                           uint32_t* __restrict__ wf1, uint32_t* __restrict__ wf2) {
    int t = blockIdx.x * blockDim.x + threadIdx.x;    // 0..4095
    if (t >= 4096) return;
    const float* W = (t < 2048) ? W1 : W2;
    uint32_t*   wf = (t < 2048) ? wf1 : wf2;
    int q = t & 2047;
    int lane = q & 63, nt = (q >> 6) & 7, kt = q >> 9;
    int n = nt * 16 + (lane & 15), g = lane >> 4;
    uint32_t frag[4];
    #pragma unroll
    for (int d = 0; d < 4; d++) {
        int kb = kt * 32 + 4 * g + (d & 1) * 2 + (d >> 1) * 16;
        frag[d] = bf16_pack(W[kb * FDIM + n], W[(kb + 1) * FDIM + n]);
    }
    ((uint4*)wf)[(kt * 8 + nt) * 64 + lane] = *(uint4*)frag;
}

// ---------------- MFMA GEMM: H(bf16) = X(bf16) @ W ----------------
// 4 waves/block, each wave owns a 16-row x 128-col band. 32 MFMAs/wave.
__global__ __launch_bounds__(256) void mfma_gemm(
        const uint32_t* __restrict__ Xp, const uint32_t* __restrict__ wf,
        uint32_t* __restrict__ H) {
    int lane = threadIdx.x & 63, wv = threadIdx.x >> 6;
    int row0 = blockIdx.x * 64 + wv * 16;
    if (row0 >= N_NODES) return;
    int r = lane & 15, g = lane >> 4;

    // A fragments: row (row0+r), k = kt*32 + 4g + {0..3, 16..19}
    const uint32_t* xrow = Xp + (size_t)(row0 + r) * HROW + 2 * g;
    FragU af[4];
    #pragma unroll
    for (int kt = 0; kt < 4; kt++) {
        uint2 lo = *(const uint2*)(xrow + kt * 16);
        uint2 hi = *(const uint2*)(xrow + kt * 16 + 8);
        af[kt].u[0] = lo.x; af[kt].u[1] = lo.y;
        af[kt].u[2] = hi.x; af[kt].u[3] = hi.y;
    }

    f32x4 acc[8] = {};
    #pragma unroll
    for (int kt = 0; kt < 4; kt++) {
        #pragma unroll
        for (int nt = 0; nt < 8; nt++) {
            FragU bfr;
            *(uint4*)bfr.u = ((const uint4*)wf)[(kt * 8 + nt) * 64 + lane];
            acc[nt] = __builtin_amdgcn_mfma_f32_16x16x32_bf16(af[kt].v, bfr.v, acc[nt], 0, 0, 0);
        }
    }

    // D layout: lane holds D[4g + j][16*nt + r]; pack col pairs via shfl_xor(1)
    #pragma unroll
    for (int nt = 0; nt < 8; nt++) {
        #pragma unroll
        for (int j = 0; j < 4; j++) {
            float v0 = acc[nt][j];
            float v1 = __shfl_xor(v0, 1, 64);
            if (!(r & 1)) {
                uint32_t p = bf16_pack(v0, v1);
                H[(size_t)(row0 + 4 * g + j) * HROW + nt * 8 + (r >> 1)] = p;
            }
        }
    }
}

// ---------------- attention scores: s = x @ (W a), wave per row ----------------
template <bool BF16IN>
__global__ __launch_bounds__(256) void score_kernel(
        const void* __restrict__ Xin, const float* __restrict__ wa_s,
        const float* __restrict__ wa_d, float* __restrict__ ssrc,
        float* __restrict__ sdst) {
    int wv = threadIdx.x >> 6, lane = threadIdx.x & 63;
    int n = blockIdx.x * 4 + wv;
    float lo, hi;
    if (BF16IN) {
        uint32_t u = ((const uint32_t*)Xin)[(size_t)n * HROW + lane];
        lo = bf16_lo(u); hi = bf16_hi(u);
    } else {
        float2 xv = ((const float2*)Xin)[(size_t)n * (FDIM / 2) + lane];
        lo = xv.x; hi = xv.y;
    }
    float2 as = *(const float2*)&wa_s[2 * lane];
    float2 ad = *(const float2*)&wa_d[2 * lane];
    float s1 = lo * as.x + hi * as.y;
    float s2 = lo * ad.x + hi * ad.y;
    #pragma unroll
    for (int off = 32; off > 0; off >>= 1) {
        s1 += __shfl_xor(s1, off, 64);
        s2 += __shfl_xor(s2, off, 64);
    }
    if (lane == 0) { ssrc[n] = s1; sdst[n] = s2; }
}

// ---------------- per-dst softmax + aggregation (bf16 rows) ----------------
__global__ __launch_bounds__(128) void gat_aggregate(
        const uint32_t* __restrict__ h, const float* __restrict__ ssrc,
        const float* __restrict__ sdst, const int* __restrict__ rowptr,
        const int* __restrict__ adj, const float* __restrict__ bias,
        uint32_t* __restrict__ out, int do_relu) {
    int wv = threadIdx.x >> 6, lane = threadIdx.x & 63;
    int n = blockIdx.x * 2 + wv;
    __shared__ __align__(16) float wbuf[2][64];
    __shared__ __align__(16) int   sbuf[2][64];

    int beg = rowptr[n], deg = rowptr[n + 1] - beg;   // >= 1 (self loop)
    float sd = sdst[n];

    float ax0 = 0.f, ay0 = 0.f, ax1 = 0.f, ay1 = 0.f;
    float dsum = 0.f;

    for (int base = 0; base < deg; base += 64) {
        int c = min(64, deg - base);
        if (lane < c) {
            int s = adj[beg + base + lane];
            float e = ssrc[s] + sd;
            e = (e >= 0.f) ? e : 0.2f * e;
            float w = __expf(e);
            wbuf[wv][lane] = w;
            sbuf[wv][lane] = s;
            dsum += w;
        }
        asm volatile("s_waitcnt lgkmcnt(0)" ::: "memory");

        int j = 0;
        for (; j + 8 <= c; j += 8) {
            float4 wa4 = *(const float4*)&wbuf[wv][j];
            float4 wb4 = *(const float4*)&wbuf[wv][j + 4];
            int4   sa4 = *(const int4*)&sbuf[wv][j];
            int4   sb4 = *(const int4*)&sbuf[wv][j + 4];
            uint32_t u0 = h[(size_t)sa4.x * HROW + lane];
            uint32_t u1 = h[(size_t)sa4.y * HROW + lane];
            uint32_t u2 = h[(size_t)sa4.z * HROW + lane];
            uint32_t u3 = h[(size_t)sa4.w * HROW + lane];
            uint32_t u4 = h[(size_t)sb4.x * HROW + lane];
            uint32_t u5 = h[(size_t)sb4.y * HROW + lane];
            uint32_t u6 = h[(size_t)sb4.z * HROW + lane];
            uint32_t u7 = h[(size_t)sb4.w * HROW + lane];
            ax0 += wa4.x * bf16_lo(u0); ay0 += wa4.x * bf16_hi(u0);
            ax1 += wa4.y * bf16_lo(u1); ay1 += wa4.y * bf16_hi(u1);
            ax0 += wa4.z * bf16_lo(u2); ay0 += wa4.z * bf16_hi(u2);
            ax1 += wa4.w * bf16_lo(u3); ay1 += wa4.w * bf16_hi(u3);
            ax0 += wb4.x * bf16_lo(u4); ay0 += wb4.x * bf16_hi(u4);
            ax1 += wb4.y * bf16_lo(u5); ay1 += wb4.y * bf16_hi(u5);
            ax0 += wb4.z * bf16_lo(u6); ay0 += wb4.z * bf16_hi(u6);
            ax1 += wb4.w * bf16_lo(u7); ay1 += wb4.w * bf16_hi(u7);
        }
        for (; j + 4 <= c; j += 4) {
            float4 w4 = *(const float4*)&wbuf[wv][j];
            int4   s4 = *(const int4*)&sbuf[wv][j];
            uint32_t u0 = h[(size_t)s4.x * HROW + lane];
            uint32_t u1 = h[(size_t)s4.y * HROW + lane];
            uint32_t u2 = h[(size_t)s4.z * HROW + lane];
            uint32_t u3 = h[(size_t)s4.w * HROW + lane];
            ax0 += w4.x * bf16_lo(u0); ay0 += w4.x * bf16_hi(u0);
            ax1 += w4.y * bf16_lo(u1); ay1 += w4.y * bf16_hi(u1);
            ax0 += w4.z * bf16_lo(u2); ay0 += w4.z * bf16_hi(u2);
            ax1 += w4.w * bf16_lo(u3); ay1 += w4.w * bf16_hi(u3);
        }
        for (; j < c; j++) {
            float w = wbuf[wv][j];
            int   s = sbuf[wv][j];
            uint32_t u = h[(size_t)s * HROW + lane];
            ax0 += w * bf16_lo(u); ay0 += w * bf16_hi(u);
        }
        asm volatile("" ::: "memory");
    }

    #pragma unroll
    for (int off = 32; off > 0; off >>= 1) dsum += __shfl_xor(dsum, off, 64);
    float inv = 1.f / dsum;
    float2 b2 = ((const float2*)bias)[lane];
    float vx = (ax0 + ax1) * inv + b2.x;
    float vy = (ay0 + ay1) * inv + b2.y;
    if (do_relu) { vx = fmaxf(vx, 0.f); vy = fmaxf(vy, 0.f); }
    out[(size_t)n * HROW + lane] = bf16_pack(vx, vy);
}

// ---------------- classifier: log_softmax(H @ Wl + bl), bf16 in ----------------
__global__ __launch_bounds__(128) void classifier_kernel(
        const uint32_t* __restrict__ H, const float* __restrict__ Wl,
        const float* __restrict__ bl, float* __restrict__ out) {
    __shared__ float xs[16][FDIM];
    int tid  = threadIdx.x;
    int row0 = blockIdx.x * 16;
    const uint32_t* Hp = H + (size_t)row0 * HROW;
    #pragma unroll
    for (int i = 0; i < 8; i++) {
        int idx = tid + 128 * i;
        uint32_t u = Hp[idx];
        int r = idx >> 6, cc = idx & 63;
        xs[r][2 * cc]     = bf16_lo(u);
        xs[r][2 * cc + 1] = bf16_hi(u);
    }
    __syncthreads();

    int c = tid & 63, hw = tid >> 6;
    float acc[8];
    float blc = (c < NCLS) ? bl[c] : 0.f;
    #pragma unroll
    for (int r = 0; r < 8; r++) acc[r] = blc;

    #pragma unroll 2
    for (int k = 0; k < FDIM; k += 4) {
        float w0 = 0.f, w1 = 0.f, w2 = 0.f, w3 = 0.f;
        if (c < NCLS) {
            w0 = Wl[(k + 0) * NCLS + c]; w1 = Wl[(k + 1) * NCLS + c];
            w2 = Wl[(k + 2) * NCLS + c]; w3 = Wl[(k + 3) * NCLS + c];
        }
        #pragma unroll
        for (int r = 0; r < 8; r++) {
            float4 xv = *(const float4*)&xs[hw * 8 + r][k];
            acc[r] += xv.x * w0 + xv.y * w1 + xv.z * w2 + xv.w * w3;
        }
    }
    #pragma unroll
    for (int r = 0; r < 8; r++) {
        float v = (c < NCLS) ? acc[r] : -INFINITY;
        float mx = v;
        #pragma unroll
        for (int off = 32; off > 0; off >>= 1) mx = fmaxf(mx, __shfl_xor(mx, off, 64));
        float ex = (c < NCLS) ? expf(v - mx) : 0.f;
        #pragma unroll
        for (int off = 32; off > 0; off >>= 1) ex += __shfl_xor(ex, off, 64);
        float ls = logf(ex);
        if (c < NCLS) out[(size_t)(row0 + hw * 8 + r) * NCLS + c] = v - mx - ls;
    }
}

// ---------------- edge_index pass-through ----------------
__global__ void edge_copy_kernel(const int* __restrict__ ei, float* __restrict__ out) {
    int i = blockIdx.x * blockDim.x + threadIdx.x;
    if (i >= (2 * N_EDGES) / 4) return;
    int4 v = ((const int4*)ei)[i];
    ((float4*)out)[i] = make_float4((float)v.x, (float)v.y, (float)v.z, (float)v.w);
}

extern "C" void kernel_launch(void* const* d_in, const int* in_sizes, int n_in,
                              void* d_out, int out_size, void* d_ws, size_t ws_size,
                              hipStream_t stream) {
    const float* x   = (const float*)d_in[0];
    const int*   ei  = (const int*)d_in[1];
    const float* W1  = (const float*)d_in[2];
    const float* a1s = (const float*)d_in[3];
    const float* a1d = (const float*)d_in[4];
    const float* b1  = (const float*)d_in[5];
    const float* W2  = (const float*)d_in[6];
    const float* a2s = (const float*)d_in[7];
    const float* a2d = (const float*)d_in[8];
    const float* b2  = (const float*)d_in[9];
    const float* Wl  = (const float*)d_in[10];
    const float* bl  = (const float*)d_in[11];
    float* out = (float*)d_out;

    char* ws = (char*)d_ws;
    size_t off = 0;
    auto alloc = [&](size_t bytes) {
        void* p = ws + off;
        off = (off + bytes + 255) & ~(size_t)255;
        return p;
    };
    int*      row_ptr = (int*)alloc((N_NODES + 1) * sizeof(int));
    int*      cursor  = (int*)alloc(N_NODES * sizeof(int));
    int*      counts  = (int*)alloc(N_NODES * sizeof(int));
    int*      bsums   = (int*)alloc(64 * sizeof(int));
    int*      adj     = (int*)alloc(TOT_E * sizeof(int));
    uint32_t* Xp      = (uint32_t*)alloc((size_t)N_NODES * HROW * sizeof(uint32_t));
    uint32_t* hA      = (uint32_t*)alloc((size_t)N_NODES * HROW * sizeof(uint32_t));
    uint32_t* hB      = (uint32_t*)alloc((size_t)N_NODES * HROW * sizeof(uint32_t));
    float*    ssrc    = (float*)alloc(N_NODES * sizeof(float));
    float*    sdst    = (float*)alloc(N_NODES * sizeof(float));
    float*    wa      = (float*)alloc(4 * FDIM * sizeof(float));
    uint32_t* wf1     = (uint32_t*)alloc(2048 * 4 * sizeof(uint32_t));
    uint32_t* wf2     = (uint32_t*)alloc(2048 * 4 * sizeof(uint32_t));
    uint32_t* hC      = Xp;   // Xp dead after layer-1 gemm; reuse for layer-2 output

    // ---- precompute ----
    hipLaunchKernelGGL(prep_wa, dim3(1), dim3(512), 0, stream, W1, a1s, a1d, W2, a2s, a2d, wa);
    hipLaunchKernelGGL(pack_x, dim3((N_NODES * HROW) / 256), dim3(256), 0, stream, x, Xp);
    hipLaunchKernelGGL(prep_wfrag, dim3(16), dim3(256), 0, stream, W1, W2, wf1, wf2);

    // ---- CSR build ----
    hipLaunchKernelGGL(init_counts, dim3((N_NODES + 255) / 256), dim3(256), 0, stream, counts);
    hipLaunchKernelGGL(hist_kernel, dim3((N_EDGES / 4 + 255) / 256), dim3(256), 0, stream, ei, counts);
    int nscan = (N_NODES + SCAN_B - 1) / SCAN_B;  // 49
    hipLaunchKernelGGL(scan1_kernel, dim3(nscan), dim3(SCAN_B), 0, stream, counts, row_ptr, bsums, N_NODES);
    hipLaunchKernelGGL(scan3_kernel, dim3(nscan), dim3(SCAN_B), 0, stream, row_ptr, bsums, cursor, N_NODES, TOT_E);
    hipLaunchKernelGGL(scatter_kernel, dim3((SCAT_T + 255) / 256), dim3(256), 0, stream, ei, cursor, adj);

    // ---- layer 1 ----
    hipLaunchKernelGGL((score_kernel<false>), dim3(N_NODES / 4), dim3(256), 0, stream,
                       (const void*)x, wa + 0, wa + FDIM, ssrc, sdst);
    hipLaunchKernelGGL(mfma_gemm, dim3((N_NODES + 63) / 64), dim3(256), 0, stream, Xp, wf1, hA);
    hipLaunchKernelGGL(gat_aggregate, dim3(N_NODES / 2), dim3(128), 0, stream,
                       hA, ssrc, sdst, row_ptr, adj, b1, hB, 1);

    // ---- layer 2 ----
    hipLaunchKernelGGL((score_kernel<true>), dim3(N_NODES / 4), dim3(256), 0, stream,
                       (const void*)hB, wa + 2 * FDIM, wa + 3 * FDIM, ssrc, sdst);
    hipLaunchKernelGGL(mfma_gemm, dim3((N_NODES + 63) / 64), dim3(256), 0, stream, hB, wf2, hA);
    hipLaunchKernelGGL(gat_aggregate, dim3(N_NODES / 2), dim3(128), 0, stream,
                       hA, ssrc, sdst, row_ptr, adj, b2, hC, 0);

    // ---- classifier + edge pass-through ----
    hipLaunchKernelGGL(classifier_kernel, dim3(N_NODES / 16), dim3(128), 0, stream, hC, Wl, bl, out);
    hipLaunchKernelGGL(edge_copy_kernel, dim3(((2 * N_EDGES) / 4 + 255) / 256), dim3(256), 0, stream,
                       ei, out + (size_t)N_NODES * NCLS);
}

// Round 6
// 291.826 us; speedup vs baseline: 1.5468x; 1.0678x over previous
//
#include <hip/hip_runtime.h>
#include <hip/hip_bf16.h>
#include <math.h>

#define N_NODES 50000
#define N_EDGES 600000
#define TOT_E   (N_EDGES + N_NODES)   // with self loops
#define FDIM    128
#define HROW    64                    // packed bf16 row: 64 uint32 = 128 bf16
#define NCLS    40
#define SCAN_B  1024

typedef __attribute__((ext_vector_type(4))) float  f32x4;
typedef __attribute__((ext_vector_type(8))) __bf16 bf16x8;
union FragU { uint32_t u[4]; bf16x8 v; };

// ---------------- bf16 pack/unpack (RNE) ----------------
__device__ inline float bf16_lo(uint32_t u) { return __uint_as_float(u << 16); }
__device__ inline float bf16_hi(uint32_t u) { return __uint_as_float(u & 0xffff0000u); }
__device__ inline uint32_t bf16_pack(float a, float b) {
    uint32_t ua = __float_as_uint(a), ub = __float_as_uint(b);
    uint32_t ra = (ua + 0x7fffu + ((ua >> 16) & 1u)) >> 16;
    uint32_t rb = (ub + 0x7fffu + ((ub >> 16) & 1u)) >> 16;
    return ra | (rb << 16);
}

// ---------------- setup: pack_x + prep_wfrag (block-partitioned) ----------------
// pack_x: 3.2M dwords / 256 = 12500 blocks exactly.
#define PACK_BLOCKS 12500
__global__ __launch_bounds__(256) void setup_kernel(
        const float* __restrict__ x, uint32_t* __restrict__ Xp,
        const float* __restrict__ W1, const float* __restrict__ W2,
        uint32_t* __restrict__ wf1, uint32_t* __restrict__ wf2) {
    int b = blockIdx.x;
    if (b < PACK_BLOCKS) {
        int i = b * 256 + threadIdx.x;
        float2 v = ((const float2*)x)[i];
        Xp[i] = bf16_pack(v.x, v.y);
        return;
    }
    // W fragment prepack: lane holds W[k][n], n = nt*16 + (lane&15),
    // k = kt*32 + 4*(lane>>4) + (e&3) + 16*(e>>2); dword d packs e=2d,2d+1.
    int t = (b - PACK_BLOCKS) * 256 + threadIdx.x;    // 0..4095
    if (t >= 4096) return;
    const float* W = (t < 2048) ? W1 : W2;
    uint32_t*   wf = (t < 2048) ? wf1 : wf2;
    int q = t & 2047;
    int lane = q & 63, nt = (q >> 6) & 7, kt = q >> 9;
    int n = nt * 16 + (lane & 15), g = lane >> 4;
    uint32_t frag[4];
    #pragma unroll
    for (int d = 0; d < 4; d++) {
        int kb = kt * 32 + 4 * g + (d & 1) * 2 + (d >> 1) * 16;
        frag[d] = bf16_pack(W[kb * FDIM + n], W[(kb + 1) * FDIM + n]);
    }
    ((uint4*)wf)[(kt * 8 + nt) * 64 + lane] = *(uint4*)frag;
}

// ---------------- CSR build ----------------
__global__ void hist_kernel(const int* __restrict__ ei, int* __restrict__ counts) {
    int i = blockIdx.x * blockDim.x + threadIdx.x;
    if (i >= N_EDGES / 4) return;
    int4 d = ((const int4*)(ei + N_EDGES))[i];
    atomicAdd(&counts[d.x], 1);
    atomicAdd(&counts[d.y], 1);
    atomicAdd(&counts[d.z], 1);
    atomicAdd(&counts[d.w], 1);
}

// shfl-based block scan; +1 folds the self loop in (counts memset to 0).
__global__ void scan1_kernel(const int* __restrict__ counts, int* __restrict__ excl,
                             int* __restrict__ bsums, int n) {
    __shared__ int ws[16];
    int gid = blockIdx.x * SCAN_B + threadIdx.x;
    int wv = threadIdx.x >> 6, lane = threadIdx.x & 63;
    int v = (gid < n) ? (counts[gid] + 1) : 0;
    int incl = v;
    #pragma unroll
    for (int off = 1; off < 64; off <<= 1) {
        int t = __shfl_up(incl, off, 64);
        if (lane >= off) incl += t;
    }
    if (lane == 63) ws[wv] = incl;
    __syncthreads();
    int woff = 0;
    for (int i = 0; i < wv; i++) woff += ws[i];
    if (gid < n) excl[gid] = woff + incl - v;
    if (threadIdx.x == SCAN_B - 1) bsums[blockIdx.x] = woff + incl;
}

__global__ void scan3_kernel(int* __restrict__ rowptr, const int* __restrict__ bsums,
                             int* __restrict__ cursor, int n, int total) {
    __shared__ int base_s;
    if (threadIdx.x < 64) {
        int v = (threadIdx.x < (int)blockIdx.x) ? bsums[threadIdx.x] : 0;
        #pragma unroll
        for (int off = 32; off > 0; off >>= 1) v += __shfl_down(v, off, 64);
        if (threadIdx.x == 0) base_s = v;
    }
    __syncthreads();
    int base = base_s;
    int gid = blockIdx.x * SCAN_B + threadIdx.x;
    if (gid < n) {
        int v = rowptr[gid] + base;
        rowptr[gid] = v;
        cursor[gid] = v;
    }
    if (gid == 0) rowptr[n] = total;
}

#define SCAT_T ((N_EDGES / 4) + N_NODES)
__global__ void scatter_kernel(const int* __restrict__ ei, int* __restrict__ cursor,
                               int* __restrict__ adj) {
    int i = blockIdx.x * blockDim.x + threadIdx.x;
    if (i >= SCAT_T) return;
    if (i < N_EDGES / 4) {
        int4 s4 = ((const int4*)ei)[i];
        int4 d4 = ((const int4*)(ei + N_EDGES))[i];
        adj[atomicAdd(&cursor[d4.x], 1)] = s4.x;
        adj[atomicAdd(&cursor[d4.y], 1)] = s4.y;
        adj[atomicAdd(&cursor[d4.z], 1)] = s4.z;
        adj[atomicAdd(&cursor[d4.w], 1)] = s4.w;
    } else {
        int nd = i - N_EDGES / 4;
        adj[atomicAdd(&cursor[nd], 1)] = nd;
    }
}

// ---------------- MFMA GEMM: H(bf16) = X(bf16) @ W, + fused scores ----------------
// 4 waves/block, each wave owns a 16-row x 128-col band. 32 MFMAs/wave.
// Scores s_src/s_dst computed from the f32 accumulator (row is wave-resident).
__global__ __launch_bounds__(256) void mfma_gemm(
        const uint32_t* __restrict__ Xp, const uint32_t* __restrict__ wf,
        const float* __restrict__ a_s, const float* __restrict__ a_d,
        uint32_t* __restrict__ H, float* __restrict__ ssrc, float* __restrict__ sdst) {
    int lane = threadIdx.x & 63, wv = threadIdx.x >> 6;
    int row0 = blockIdx.x * 64 + wv * 16;
    if (row0 >= N_NODES) return;
    int r = lane & 15, g = lane >> 4;

    // A fragments: row (row0+r), k = kt*32 + 4g + {0..3, 16..19}
    const uint32_t* xrow = Xp + (size_t)(row0 + r) * HROW + 2 * g;
    FragU af[4];
    #pragma unroll
    for (int kt = 0; kt < 4; kt++) {
        uint2 lo = *(const uint2*)(xrow + kt * 16);
        uint2 hi = *(const uint2*)(xrow + kt * 16 + 8);
        af[kt].u[0] = lo.x; af[kt].u[1] = lo.y;
        af[kt].u[2] = hi.x; af[kt].u[3] = hi.y;
    }

    f32x4 acc[8] = {};
    #pragma unroll
    for (int kt = 0; kt < 4; kt++) {
        #pragma unroll
        for (int nt = 0; nt < 8; nt++) {
            FragU bfr;
            *(uint4*)bfr.u = ((const uint4*)wf)[(kt * 8 + nt) * 64 + lane];
            acc[nt] = __builtin_amdgcn_mfma_f32_16x16x32_bf16(af[kt].v, bfr.v, acc[nt], 0, 0, 0);
        }
    }

    // ---- fused attention scores: D layout lane holds D[4g+j][16*nt+r] ----
    float av_s[8], av_d[8];
    #pragma unroll
    for (int nt = 0; nt < 8; nt++) { av_s[nt] = a_s[16 * nt + r]; av_d[nt] = a_d[16 * nt + r]; }
    #pragma unroll
    for (int j = 0; j < 4; j++) {
        float ps = 0.f, pd = 0.f;
        #pragma unroll
        for (int nt = 0; nt < 8; nt++) { ps += acc[nt][j] * av_s[nt]; pd += acc[nt][j] * av_d[nt]; }
        #pragma unroll
        for (int off = 1; off < 16; off <<= 1) {   // reduce within 16-lane group
            ps += __shfl_xor(ps, off, 64);
            pd += __shfl_xor(pd, off, 64);
        }
        if (r == 0) { ssrc[row0 + 4 * g + j] = ps; sdst[row0 + 4 * g + j] = pd; }
    }

    // ---- pack to bf16: col pairs via shfl_xor(1) ----
    #pragma unroll
    for (int nt = 0; nt < 8; nt++) {
        #pragma unroll
        for (int j = 0; j < 4; j++) {
            float v0 = acc[nt][j];
            float v1 = __shfl_xor(v0, 1, 64);
            if (!(r & 1)) {
                uint32_t p = bf16_pack(v0, v1);
                H[(size_t)(row0 + 4 * g + j) * HROW + nt * 8 + (r >> 1)] = p;
            }
        }
    }
}

// ---------------- per-dst softmax + aggregation (bf16 rows, uint4 gather) ----------------
// Wave per node, 2 nodes/block. 16 lanes/row x uint4 loads: 4 rows in flight per
// instruction, 4 loads/lane per 16-edge group. No max pass (shift-invariant).
__global__ __launch_bounds__(128) void gat_aggregate(
        const uint32_t* __restrict__ h, const float* __restrict__ ssrc,
        const float* __restrict__ sdst, const int* __restrict__ rowptr,
        const int* __restrict__ adj, const float* __restrict__ bias,
        uint32_t* __restrict__ out, int do_relu) {
    int wv = threadIdx.x >> 6, lane = threadIdx.x & 63;
    int sub = lane >> 4, l16 = lane & 15;
    int n = blockIdx.x * 2 + wv;
    __shared__ __align__(16) float wbuf[2][64];
    __shared__ __align__(16) int   sbuf[2][64];

    int beg = rowptr[n], deg = rowptr[n + 1] - beg;   // >= 1 (self loop)
    float sd = sdst[n];
    const uint4* h4 = (const uint4*)h;                // row = 16 uint4

    float acc[8] = {};
    float dsum = 0.f;

    for (int base = 0; base < deg; base += 64) {
        int c = min(64, deg - base);
        if (lane < c) {
            int s = adj[beg + base + lane];
            float e = ssrc[s] + sd;
            e = (e >= 0.f) ? e : 0.2f * e;
            float w = __expf(e);
            wbuf[wv][lane] = w;
            sbuf[wv][lane] = s;
            dsum += w;
        }
        // wave-synchronous LDS: drain ds_writes before cross-lane reads.
        asm volatile("s_waitcnt lgkmcnt(0)" ::: "memory");

        int j = 0;
        for (; j + 16 <= c; j += 16) {               // 16 edges: 4 per sub-group
            float4 w4 = *(const float4*)&wbuf[wv][j + 4 * sub];
            int4   s4 = *(const int4*)&sbuf[wv][j + 4 * sub];
            uint4 u0 = h4[(size_t)s4.x * 16 + l16];
            uint4 u1 = h4[(size_t)s4.y * 16 + l16];
            uint4 u2 = h4[(size_t)s4.z * 16 + l16];
            uint4 u3 = h4[(size_t)s4.w * 16 + l16];
            acc[0] += w4.x * bf16_lo(u0.x) + w4.y * bf16_lo(u1.x) + w4.z * bf16_lo(u2.x) + w4.w * bf16_lo(u3.x);
            acc[1] += w4.x * bf16_hi(u0.x) + w4.y * bf16_hi(u1.x) + w4.z * bf16_hi(u2.x) + w4.w * bf16_hi(u3.x);
            acc[2] += w4.x * bf16_lo(u0.y) + w4.y * bf16_lo(u1.y) + w4.z * bf16_lo(u2.y) + w4.w * bf16_lo(u3.y);
            acc[3] += w4.x * bf16_hi(u0.y) + w4.y * bf16_hi(u1.y) + w4.z * bf16_hi(u2.y) + w4.w * bf16_hi(u3.y);
            acc[4] += w4.x * bf16_lo(u0.z) + w4.y * bf16_lo(u1.z) + w4.z * bf16_lo(u2.z) + w4.w * bf16_lo(u3.z);
            acc[5] += w4.x * bf16_hi(u0.z) + w4.y * bf16_hi(u1.z) + w4.z * bf16_hi(u2.z) + w4.w * bf16_hi(u3.z);
            acc[6] += w4.x * bf16_lo(u0.w) + w4.y * bf16_lo(u1.w) + w4.z * bf16_lo(u2.w) + w4.w * bf16_lo(u3.w);
            acc[7] += w4.x * bf16_hi(u0.w) + w4.y * bf16_hi(u1.w) + w4.z * bf16_hi(u2.w) + w4.w * bf16_hi(u3.w);
        }
        for (; j < c; j += 4) {                      // remainder: 1 edge per sub-group
            int e = j + sub;
            if (e < c) {
                float w = wbuf[wv][e];
                int   s = sbuf[wv][e];
                uint4 u = h4[(size_t)s * 16 + l16];
                acc[0] += w * bf16_lo(u.x); acc[1] += w * bf16_hi(u.x);
                acc[2] += w * bf16_lo(u.y); acc[3] += w * bf16_hi(u.y);
                acc[4] += w * bf16_lo(u.z); acc[5] += w * bf16_hi(u.z);
                acc[6] += w * bf16_lo(u.w); acc[7] += w * bf16_hi(u.w);
            }
        }
        asm volatile("" ::: "memory");
    }

    // combine the 4 sub-group partial sums (same cols, different edges)
    #pragma unroll
    for (int k = 0; k < 8; k++) {
        acc[k] += __shfl_xor(acc[k], 16, 64);
        acc[k] += __shfl_xor(acc[k], 32, 64);
    }
    #pragma unroll
    for (int off = 32; off > 0; off >>= 1) dsum += __shfl_xor(dsum, off, 64);

    if (sub == 0) {
        float inv = 1.f / dsum;
        float4 b0 = *(const float4*)&bias[l16 * 8];
        float4 b1 = *(const float4*)&bias[l16 * 8 + 4];
        float v0 = acc[0] * inv + b0.x, v1 = acc[1] * inv + b0.y;
        float v2 = acc[2] * inv + b0.z, v3 = acc[3] * inv + b0.w;
        float v4 = acc[4] * inv + b1.x, v5 = acc[5] * inv + b1.y;
        float v6 = acc[6] * inv + b1.z, v7 = acc[7] * inv + b1.w;
        if (do_relu) {
            v0 = fmaxf(v0, 0.f); v1 = fmaxf(v1, 0.f); v2 = fmaxf(v2, 0.f); v3 = fmaxf(v3, 0.f);
            v4 = fmaxf(v4, 0.f); v5 = fmaxf(v5, 0.f); v6 = fmaxf(v6, 0.f); v7 = fmaxf(v7, 0.f);
        }
        uint4 o;
        o.x = bf16_pack(v0, v1); o.y = bf16_pack(v2, v3);
        o.z = bf16_pack(v4, v5); o.w = bf16_pack(v6, v7);
        ((uint4*)out)[(size_t)n * 16 + l16] = o;
    }
}

// ---------------- classifier + edge pass-through (fused launch) ----------------
#define CLS_BLOCKS  (N_NODES / 16)                 // 3125
#define EDGE_ITEMS  ((2 * N_EDGES) / 4)            // 300000 int4
#define EDGE_BLOCKS ((EDGE_ITEMS + 127) / 128)     // 2344
__global__ __launch_bounds__(128) void classifier_edge_kernel(
        const uint32_t* __restrict__ H, const float* __restrict__ Wl,
        const float* __restrict__ bl, const int* __restrict__ ei,
        float* __restrict__ out, float* __restrict__ eout) {
    if (blockIdx.x >= CLS_BLOCKS) {
        int i = (blockIdx.x - CLS_BLOCKS) * 128 + threadIdx.x;
        if (i < EDGE_ITEMS) {
            int4 v = ((const int4*)ei)[i];
            ((float4*)eout)[i] = make_float4((float)v.x, (float)v.y, (float)v.z, (float)v.w);
        }
        return;
    }
    __shared__ float xs[16][FDIM];
    int tid  = threadIdx.x;
    int row0 = blockIdx.x * 16;
    const uint32_t* Hp = H + (size_t)row0 * HROW;
    #pragma unroll
    for (int i = 0; i < 8; i++) {
        int idx = tid + 128 * i;
        uint32_t u = Hp[idx];
        int r = idx >> 6, cc = idx & 63;
        xs[r][2 * cc]     = bf16_lo(u);
        xs[r][2 * cc + 1] = bf16_hi(u);
    }
    __syncthreads();

    int c = tid & 63, hw = tid >> 6;
    float acc[8];
    float blc = (c < NCLS) ? bl[c] : 0.f;
    #pragma unroll
    for (int r = 0; r < 8; r++) acc[r] = blc;

    #pragma unroll 2
    for (int k = 0; k < FDIM; k += 4) {
        float w0 = 0.f, w1 = 0.f, w2 = 0.f, w3 = 0.f;
        if (c < NCLS) {
            w0 = Wl[(k + 0) * NCLS + c]; w1 = Wl[(k + 1) * NCLS + c];
            w2 = Wl[(k + 2) * NCLS + c]; w3 = Wl[(k + 3) * NCLS + c];
        }
        #pragma unroll
        for (int r = 0; r < 8; r++) {
            float4 xv = *(const float4*)&xs[hw * 8 + r][k];
            acc[r] += xv.x * w0 + xv.y * w1 + xv.z * w2 + xv.w * w3;
        }
    }
    #pragma unroll
    for (int r = 0; r < 8; r++) {
        float v = (c < NCLS) ? acc[r] : -INFINITY;
        float mx = v;
        #pragma unroll
        for (int off = 32; off > 0; off >>= 1) mx = fmaxf(mx, __shfl_xor(mx, off, 64));
        float ex = (c < NCLS) ? expf(v - mx) : 0.f;
        #pragma unroll
        for (int off = 32; off > 0; off >>= 1) ex += __shfl_xor(ex, off, 64);
        float ls = logf(ex);
        if (c < NCLS) out[(size_t)(row0 + hw * 8 + r) * NCLS + c] = v - mx - ls;
    }
}

extern "C" void kernel_launch(void* const* d_in, const int* in_sizes, int n_in,
                              void* d_out, int out_size, void* d_ws, size_t ws_size,
                              hipStream_t stream) {
    const float* x   = (const float*)d_in[0];
    const int*   ei  = (const int*)d_in[1];
    const float* W1  = (const float*)d_in[2];
    const float* a1s = (const float*)d_in[3];
    const float* a1d = (const float*)d_in[4];
    const float* b1  = (const float*)d_in[5];
    const float* W2  = (const float*)d_in[6];
    const float* a2s = (const float*)d_in[7];
    const float* a2d = (const float*)d_in[8];
    const float* b2  = (const float*)d_in[9];
    const float* Wl  = (const float*)d_in[10];
    const float* bl  = (const float*)d_in[11];
    float* out = (float*)d_out;

    char* ws = (char*)d_ws;
    size_t off = 0;
    auto alloc = [&](size_t bytes) {
        void* p = ws + off;
        off = (off + bytes + 255) & ~(size_t)255;
        return p;
    };
    int*      row_ptr = (int*)alloc((N_NODES + 1) * sizeof(int));
    int*      cursor  = (int*)alloc(N_NODES * sizeof(int));
    int*      counts  = (int*)alloc(N_NODES * sizeof(int));
    int*      bsums   = (int*)alloc(64 * sizeof(int));
    int*      adj     = (int*)alloc(TOT_E * sizeof(int));
    uint32_t* Xp      = (uint32_t*)alloc((size_t)N_NODES * HROW * sizeof(uint32_t));
    uint32_t* hA      = (uint32_t*)alloc((size_t)N_NODES * HROW * sizeof(uint32_t));
    uint32_t* hB      = (uint32_t*)alloc((size_t)N_NODES * HROW * sizeof(uint32_t));
    float*    ssrc    = (float*)alloc(N_NODES * sizeof(float));
    float*    sdst    = (float*)alloc(N_NODES * sizeof(float));
    uint32_t* wf1     = (uint32_t*)alloc(2048 * 4 * sizeof(uint32_t));
    uint32_t* wf2     = (uint32_t*)alloc(2048 * 4 * sizeof(uint32_t));
    uint32_t* hC      = Xp;   // Xp dead after layer-1 gemm; reuse for layer-2 output

    // ---- setup: pack x to bf16, prepack W frags; counts = 0 (self loop in scan) ----
    hipMemsetAsync(counts, 0, N_NODES * sizeof(int), stream);
    hipLaunchKernelGGL(setup_kernel, dim3(PACK_BLOCKS + 16), dim3(256), 0, stream,
                       x, Xp, W1, W2, wf1, wf2);

    // ---- CSR build ----
    hipLaunchKernelGGL(hist_kernel, dim3((N_EDGES / 4 + 255) / 256), dim3(256), 0, stream, ei, counts);
    int nscan = (N_NODES + SCAN_B - 1) / SCAN_B;  // 49
    hipLaunchKernelGGL(scan1_kernel, dim3(nscan), dim3(SCAN_B), 0, stream, counts, row_ptr, bsums, N_NODES);
    hipLaunchKernelGGL(scan3_kernel, dim3(nscan), dim3(SCAN_B), 0, stream, row_ptr, bsums, cursor, N_NODES, TOT_E);
    hipLaunchKernelGGL(scatter_kernel, dim3((SCAT_T + 255) / 256), dim3(256), 0, stream, ei, cursor, adj);

    // ---- layer 1 ----
    hipLaunchKernelGGL(mfma_gemm, dim3((N_NODES + 63) / 64), dim3(256), 0, stream,
                       Xp, wf1, a1s, a1d, hA, ssrc, sdst);
    hipLaunchKernelGGL(gat_aggregate, dim3(N_NODES / 2), dim3(128), 0, stream,
                       hA, ssrc, sdst, row_ptr, adj, b1, hB, 1);

    // ---- layer 2 ----
    hipLaunchKernelGGL(mfma_gemm, dim3((N_NODES + 63) / 64), dim3(256), 0, stream,
                       hB, wf2, a2s, a2d, hA, ssrc, sdst);
    hipLaunchKernelGGL(gat_aggregate, dim3(N_NODES / 2), dim3(128), 0, stream,
                       hA, ssrc, sdst, row_ptr, adj, b2, hC, 0);

    // ---- classifier + edge pass-through (one launch) ----
    hipLaunchKernelGGL(classifier_edge_kernel, dim3(CLS_BLOCKS + EDGE_BLOCKS), dim3(128), 0, stream,
                       hC, Wl, bl, ei, out, out + (size_t)N_NODES * NCLS);
}

// Round 8
// 285.718 us; speedup vs baseline: 1.5798x; 1.0214x over previous
//
#include <hip/hip_runtime.h>
#include <hip/hip_bf16.h>
#include <math.h>

#define N_NODES 50000
#define N_EDGES 600000
#define TOT_E   (N_EDGES + N_NODES)   // with self loops
#define FDIM    128
#define HROW    64                    // packed bf16 row: 64 uint32 = 128 bf16
#define NCLS    40
#define SCAN_B  1024

typedef __attribute__((ext_vector_type(4))) float  f32x4;
typedef __attribute__((ext_vector_type(8))) __bf16 bf16x8;
union FragU { uint32_t u[4]; bf16x8 v; };

// ---------------- bf16 pack/unpack (RNE) ----------------
__device__ inline float bf16_lo(uint32_t u) { return __uint_as_float(u << 16); }
__device__ inline float bf16_hi(uint32_t u) { return __uint_as_float(u & 0xffff0000u); }
__device__ inline uint32_t bf16_pack(float a, float b) {
    uint32_t ua = __float_as_uint(a), ub = __float_as_uint(b);
    uint32_t ra = (ua + 0x7fffu + ((ua >> 16) & 1u)) >> 16;
    uint32_t rb = (ub + 0x7fffu + ((ub >> 16) & 1u)) >> 16;
    return ra | (rb << 16);
}

// ---------------- per-wave aggregation inner loop (shared K5/K6) ----------------
// 16 lanes/row x uint4: 4 rows in flight per load instruction. No max pass
// (softmax shift-invariant; |e| <= ~10 here so exp(e) is f32-safe).
__device__ __forceinline__ void wave_agg_loop(
        const uint4* __restrict__ h4, const float* __restrict__ ssrc,
        const int* __restrict__ adj, float sd, int beg, int deg,
        float* wb, int* sb, int lane, int sub, int l16,
        float acc[8], float& dsum) {
    for (int base = 0; base < deg; base += 64) {
        int c = min(64, deg - base);
        if (lane < c) {
            int s = adj[beg + base + lane];
            float e = ssrc[s] + sd;
            e = (e >= 0.f) ? e : 0.2f * e;
            float w = __expf(e);
            wb[lane] = w;
            sb[lane] = s;
            dsum += w;
        }
        // wave-synchronous LDS: drain ds_writes before cross-lane reads.
        asm volatile("s_waitcnt lgkmcnt(0)" ::: "memory");

        int j = 0;
        for (; j + 16 <= c; j += 16) {               // 16 edges: 4 per sub-group
            float4 w4 = *(const float4*)&wb[j + 4 * sub];
            int4   s4 = *(const int4*)&sb[j + 4 * sub];
            uint4 u0 = h4[(size_t)s4.x * 16 + l16];
            uint4 u1 = h4[(size_t)s4.y * 16 + l16];
            uint4 u2 = h4[(size_t)s4.z * 16 + l16];
            uint4 u3 = h4[(size_t)s4.w * 16 + l16];
            acc[0] += w4.x * bf16_lo(u0.x) + w4.y * bf16_lo(u1.x) + w4.z * bf16_lo(u2.x) + w4.w * bf16_lo(u3.x);
            acc[1] += w4.x * bf16_hi(u0.x) + w4.y * bf16_hi(u1.x) + w4.z * bf16_hi(u2.x) + w4.w * bf16_hi(u3.x);
            acc[2] += w4.x * bf16_lo(u0.y) + w4.y * bf16_lo(u1.y) + w4.z * bf16_lo(u2.y) + w4.w * bf16_lo(u3.y);
            acc[3] += w4.x * bf16_hi(u0.y) + w4.y * bf16_hi(u1.y) + w4.z * bf16_hi(u2.y) + w4.w * bf16_hi(u3.y);
            acc[4] += w4.x * bf16_lo(u0.z) + w4.y * bf16_lo(u1.z) + w4.z * bf16_lo(u2.z) + w4.w * bf16_lo(u3.z);
            acc[5] += w4.x * bf16_hi(u0.z) + w4.y * bf16_hi(u1.z) + w4.z * bf16_hi(u2.z) + w4.w * bf16_hi(u3.z);
            acc[6] += w4.x * bf16_lo(u0.w) + w4.y * bf16_lo(u1.w) + w4.z * bf16_lo(u2.w) + w4.w * bf16_lo(u3.w);
            acc[7] += w4.x * bf16_hi(u0.w) + w4.y * bf16_hi(u1.w) + w4.z * bf16_hi(u2.w) + w4.w * bf16_hi(u3.w);
        }
        for (; j < c; j += 4) {                      // remainder: 1 edge per sub-group
            int e = j + sub;
            if (e < c) {
                float w = wb[e];
                int   s = sb[e];
                uint4 u = h4[(size_t)s * 16 + l16];
                acc[0] += w * bf16_lo(u.x); acc[1] += w * bf16_hi(u.x);
                acc[2] += w * bf16_lo(u.y); acc[3] += w * bf16_hi(u.y);
                acc[4] += w * bf16_lo(u.z); acc[5] += w * bf16_hi(u.z);
                acc[6] += w * bf16_lo(u.w); acc[7] += w * bf16_hi(u.w);
            }
        }
        asm volatile("" ::: "memory");
    }
    // combine the 4 sub-group partial sums (same cols, different edges)
    #pragma unroll
    for (int k = 0; k < 8; k++) {
        acc[k] += __shfl_xor(acc[k], 16, 64);
        acc[k] += __shfl_xor(acc[k], 32, 64);
    }
    #pragma unroll
    for (int off = 32; off > 0; off >>= 1) dsum += __shfl_xor(dsum, off, 64);
}

// ================= K1: pack_x ∥ W-frag prepack ∥ hist =================
#define PACK_BLOCKS  12500                          // 3.2M dwords / 256
#define WFRAG_BLOCKS 16
#define HIST_BLOCKS  ((N_EDGES / 4 + 255) / 256)    // 586
__global__ __launch_bounds__(256) void k1_setup_hist(
        const float* __restrict__ x, uint32_t* __restrict__ Xp,
        const float* __restrict__ W1, const float* __restrict__ W2,
        uint32_t* __restrict__ wf1, uint32_t* __restrict__ wf2,
        const int* __restrict__ ei, int* __restrict__ counts) {
    int b = blockIdx.x;
    if (b < PACK_BLOCKS) {
        int i = b * 256 + threadIdx.x;
        float2 v = ((const float2*)x)[i];
        Xp[i] = bf16_pack(v.x, v.y);
        return;
    }
    if (b < PACK_BLOCKS + WFRAG_BLOCKS) {
        // lane holds W[k][n]: n = nt*16 + (lane&15), k = kt*32 + 4g + {e&3} + 16*(e>>2)
        int t = (b - PACK_BLOCKS) * 256 + threadIdx.x;    // 0..4095
        if (t >= 4096) return;
        const float* W = (t < 2048) ? W1 : W2;
        uint32_t*   wf = (t < 2048) ? wf1 : wf2;
        int q = t & 2047;
        int lane = q & 63, nt = (q >> 6) & 7, kt = q >> 9;
        int n = nt * 16 + (lane & 15), g = lane >> 4;
        uint32_t frag[4];
        #pragma unroll
        for (int d = 0; d < 4; d++) {
            int kb = kt * 32 + 4 * g + (d & 1) * 2 + (d >> 1) * 16;
            frag[d] = bf16_pack(W[kb * FDIM + n], W[(kb + 1) * FDIM + n]);
        }
        ((uint4*)wf)[(kt * 8 + nt) * 64 + lane] = *(uint4*)frag;
        return;
    }
    int i = (b - PACK_BLOCKS - WFRAG_BLOCKS) * 256 + threadIdx.x;
    if (i >= N_EDGES / 4) return;
    int4 d = ((const int4*)(ei + N_EDGES))[i];
    atomicAdd(&counts[d.x], 1);
    atomicAdd(&counts[d.y], 1);
    atomicAdd(&counts[d.z], 1);
    atomicAdd(&counts[d.w], 1);
}

// ================= K2/K3: scan =================
// shfl-based block scan; +1 folds the self loop in (counts memset to 0).
__global__ void scan1_kernel(const int* __restrict__ counts, int* __restrict__ excl,
                             int* __restrict__ bsums, int n) {
    __shared__ int ws[16];
    int gid = blockIdx.x * SCAN_B + threadIdx.x;
    int wv = threadIdx.x >> 6, lane = threadIdx.x & 63;
    int v = (gid < n) ? (counts[gid] + 1) : 0;
    int incl = v;
    #pragma unroll
    for (int off = 1; off < 64; off <<= 1) {
        int t = __shfl_up(incl, off, 64);
        if (lane >= off) incl += t;
    }
    if (lane == 63) ws[wv] = incl;
    __syncthreads();
    int woff = 0;
    for (int i = 0; i < wv; i++) woff += ws[i];
    if (gid < n) excl[gid] = woff + incl - v;
    if (threadIdx.x == SCAN_B - 1) bsums[blockIdx.x] = woff + incl;
}

__global__ void scan3_kernel(int* __restrict__ rowptr, const int* __restrict__ bsums,
                             int* __restrict__ cursor, int n, int total) {
    __shared__ int base_s;
    if (threadIdx.x < 64) {
        int v = (threadIdx.x < (int)blockIdx.x) ? bsums[threadIdx.x] : 0;
        #pragma unroll
        for (int off = 32; off > 0; off >>= 1) v += __shfl_down(v, off, 64);
        if (threadIdx.x == 0) base_s = v;
    }
    __syncthreads();
    int base = base_s;
    int gid = blockIdx.x * SCAN_B + threadIdx.x;
    if (gid < n) {
        int v = rowptr[gid] + base;
        rowptr[gid] = v;
        cursor[gid] = v;
    }
    if (gid == 0) rowptr[n] = total;
}

// ================= K4: scatter ∥ mfma_gemm1(+scores1) ∥ edge copy =================
#define SCAT_T      ((N_EDGES / 4) + N_NODES)       // 200000
#define SCAT_BLOCKS ((SCAT_T + 255) / 256)          // 782
#define GEMM_BLOCKS ((N_NODES + 63) / 64)           // 782
#define EDGE_ITEMS  ((2 * N_EDGES) / 4)             // 300000 int4
#define EDGE_BLOCKS ((EDGE_ITEMS + 255) / 256)      // 1172
__global__ __launch_bounds__(256) void k4_scatter_gemm_edge(
        const int* __restrict__ ei, int* __restrict__ cursor, int* __restrict__ adj,
        const uint32_t* __restrict__ Xp, const uint32_t* __restrict__ wf,
        const float* __restrict__ a_s, const float* __restrict__ a_d,
        uint32_t* __restrict__ H, float* __restrict__ ssrc, float* __restrict__ sdst,
        float* __restrict__ eout) {
    int b = blockIdx.x;
    if (b < SCAT_BLOCKS) {
        int i = b * 256 + threadIdx.x;
        if (i >= SCAT_T) return;
        if (i < N_EDGES / 4) {
            int4 s4 = ((const int4*)ei)[i];
            int4 d4 = ((const int4*)(ei + N_EDGES))[i];
            adj[atomicAdd(&cursor[d4.x], 1)] = s4.x;
            adj[atomicAdd(&cursor[d4.y], 1)] = s4.y;
            adj[atomicAdd(&cursor[d4.z], 1)] = s4.z;
            adj[atomicAdd(&cursor[d4.w], 1)] = s4.w;
        } else {
            int nd = i - N_EDGES / 4;
            adj[atomicAdd(&cursor[nd], 1)] = nd;
        }
        return;
    }
    if (b < SCAT_BLOCKS + GEMM_BLOCKS) {
        // 4 waves/block, each wave a 16-row x 128-col band; 32 MFMAs/wave.
        int lane = threadIdx.x & 63, wv = threadIdx.x >> 6;
        int row0 = (b - SCAT_BLOCKS) * 64 + wv * 16;
        if (row0 >= N_NODES) return;
        int r = lane & 15, g = lane >> 4;

        const uint32_t* xrow = Xp + (size_t)(row0 + r) * HROW + 2 * g;
        FragU af[4];
        #pragma unroll
        for (int kt = 0; kt < 4; kt++) {
            uint2 lo = *(const uint2*)(xrow + kt * 16);
            uint2 hi = *(const uint2*)(xrow + kt * 16 + 8);
            af[kt].u[0] = lo.x; af[kt].u[1] = lo.y;
            af[kt].u[2] = hi.x; af[kt].u[3] = hi.y;
        }
        f32x4 acc[8] = {};
        #pragma unroll
        for (int kt = 0; kt < 4; kt++) {
            #pragma unroll
            for (int nt = 0; nt < 8; nt++) {
                FragU bfr;
                *(uint4*)bfr.u = ((const uint4*)wf)[(kt * 8 + nt) * 64 + lane];
                acc[nt] = __builtin_amdgcn_mfma_f32_16x16x32_bf16(af[kt].v, bfr.v, acc[nt], 0, 0, 0);
            }
        }
        // fused scores: D layout lane holds D[4g+j][16*nt+r]
        float av_s[8], av_d[8];
        #pragma unroll
        for (int nt = 0; nt < 8; nt++) { av_s[nt] = a_s[16 * nt + r]; av_d[nt] = a_d[16 * nt + r]; }
        #pragma unroll
        for (int j = 0; j < 4; j++) {
            float ps = 0.f, pd = 0.f;
            #pragma unroll
            for (int nt = 0; nt < 8; nt++) { ps += acc[nt][j] * av_s[nt]; pd += acc[nt][j] * av_d[nt]; }
            #pragma unroll
            for (int off = 1; off < 16; off <<= 1) {
                ps += __shfl_xor(ps, off, 64);
                pd += __shfl_xor(pd, off, 64);
            }
            if (r == 0) { ssrc[row0 + 4 * g + j] = ps; sdst[row0 + 4 * g + j] = pd; }
        }
        // pack to bf16: col pairs via shfl_xor(1)
        #pragma unroll
        for (int nt = 0; nt < 8; nt++) {
            #pragma unroll
            for (int j = 0; j < 4; j++) {
                float v0 = acc[nt][j];
                float v1 = __shfl_xor(v0, 1, 64);
                if (!(r & 1))
                    H[(size_t)(row0 + 4 * g + j) * HROW + nt * 8 + (r >> 1)] = bf16_pack(v0, v1);
            }
        }
        return;
    }
    int i = (b - SCAT_BLOCKS - GEMM_BLOCKS) * 256 + threadIdx.x;
    if (i < EDGE_ITEMS) {
        int4 v = ((const int4*)ei)[i];
        ((float4*)eout)[i] = make_float4((float)v.x, (float)v.y, (float)v.z, (float)v.w);
    }
}

// ================= K5: agg1 + gemm2 + scores2 (fused) =================
// Block = 4 waves = 16 nodes. Each wave aggregates 4 nodes sequentially into
// LDS rowbuf (bf16, +4-dword row pad -> 2-way banks max on frag reads), then
// the block MFMAs the 16-row tile with wf2 (nt-split across waves) and reduces
// the attention scores for the next layer in LDS. Kills the hB round-trip.
__global__ __launch_bounds__(256) void k5_agg_gemm(
        const uint32_t* __restrict__ h, const float* __restrict__ ssrc,
        const float* __restrict__ sdst, const int* __restrict__ rowptr,
        const int* __restrict__ adj, const float* __restrict__ bias,
        const uint32_t* __restrict__ wf, const float* __restrict__ a_s,
        const float* __restrict__ a_d, uint32_t* __restrict__ Hout,
        float* __restrict__ ssrc2, float* __restrict__ sdst2) {
    int tid = threadIdx.x;
    int wv = tid >> 6, lane = tid & 63;
    int sub = lane >> 4, l16 = lane & 15;
    int row0 = blockIdx.x * 16;
    __shared__ __align__(16) float    wbuf[4][64];
    __shared__ __align__(16) int      sbuf[4][64];
    __shared__ __align__(16) uint32_t rowbuf[16][68];   // 64 data + 4 pad dwords
    __shared__ float scS[4][16], scD[4][16];
    const uint4* h4 = (const uint4*)h;

    for (int i = 0; i < 4; i++) {
        int row = wv * 4 + i;
        int n = row0 + row;
        int beg = rowptr[n], deg = rowptr[n + 1] - beg;  // >= 1 (self loop)
        float acc[8] = {};
        float dsum = 0.f;
        wave_agg_loop(h4, ssrc, adj, sdst[n], beg, deg, wbuf[wv], sbuf[wv],
                      lane, sub, l16, acc, dsum);
        if (sub == 0) {
            float inv = 1.f / dsum;
            float4 b0 = *(const float4*)&bias[l16 * 8];
            float4 b1 = *(const float4*)&bias[l16 * 8 + 4];
            float v0 = fmaxf(acc[0] * inv + b0.x, 0.f), v1 = fmaxf(acc[1] * inv + b0.y, 0.f);
            float v2 = fmaxf(acc[2] * inv + b0.z, 0.f), v3 = fmaxf(acc[3] * inv + b0.w, 0.f);
            float v4 = fmaxf(acc[4] * inv + b1.x, 0.f), v5 = fmaxf(acc[5] * inv + b1.y, 0.f);
            float v6 = fmaxf(acc[6] * inv + b1.z, 0.f), v7 = fmaxf(acc[7] * inv + b1.w, 0.f);
            uint4 o;
            o.x = bf16_pack(v0, v1); o.y = bf16_pack(v2, v3);
            o.z = bf16_pack(v4, v5); o.w = bf16_pack(v6, v7);
            *(uint4*)&rowbuf[row][l16 * 4] = o;
        }
    }
    __syncthreads();

    // ---- phase 2: 16x128 GEMM tile, wave wv owns nt = 2wv, 2wv+1 ----
    int r = lane & 15, g = lane >> 4;
    FragU af[4];
    #pragma unroll
    for (int kt = 0; kt < 4; kt++) {
        uint2 lo = *(const uint2*)&rowbuf[r][kt * 16 + 2 * g];
        uint2 hi = *(const uint2*)&rowbuf[r][kt * 16 + 2 * g + 8];
        af[kt].u[0] = lo.x; af[kt].u[1] = lo.y;
        af[kt].u[2] = hi.x; af[kt].u[3] = hi.y;
    }
    f32x4 acc2[2] = {};
    #pragma unroll
    for (int kt = 0; kt < 4; kt++) {
        #pragma unroll
        for (int t = 0; t < 2; t++) {
            int nt = 2 * wv + t;
            FragU bfr;
            *(uint4*)bfr.u = ((const uint4*)wf)[(kt * 8 + nt) * 64 + lane];
            acc2[t] = __builtin_amdgcn_mfma_f32_16x16x32_bf16(af[kt].v, bfr.v, acc2[t], 0, 0, 0);
        }
    }
    // ---- phase 3: score partials (this wave's 32 cols), cross-wave via LDS ----
    float as0 = a_s[16 * (2 * wv) + r], as1 = a_s[16 * (2 * wv + 1) + r];
    float ad0 = a_d[16 * (2 * wv) + r], ad1 = a_d[16 * (2 * wv + 1) + r];
    #pragma unroll
    for (int j = 0; j < 4; j++) {
        float ps = acc2[0][j] * as0 + acc2[1][j] * as1;
        float pd = acc2[0][j] * ad0 + acc2[1][j] * ad1;
        #pragma unroll
        for (int off = 1; off < 16; off <<= 1) {
            ps += __shfl_xor(ps, off, 64);
            pd += __shfl_xor(pd, off, 64);
        }
        if (r == 0) { scS[wv][4 * g + j] = ps; scD[wv][4 * g + j] = pd; }
    }
    // ---- phase 4: bf16 pack + global H write (cols 32wv..32wv+31) ----
    #pragma unroll
    for (int t = 0; t < 2; t++) {
        #pragma unroll
        for (int j = 0; j < 4; j++) {
            float v0 = acc2[t][j];
            float v1 = __shfl_xor(v0, 1, 64);
            if (!(r & 1))
                Hout[(size_t)(row0 + 4 * g + j) * HROW + (2 * wv + t) * 8 + (r >> 1)] = bf16_pack(v0, v1);
        }
    }
    __syncthreads();
    if (tid < 16)
        ssrc2[row0 + tid] = scS[0][tid] + scS[1][tid] + scS[2][tid] + scS[3][tid];
    else if (tid < 32) {
        int q = tid - 16;
        sdst2[row0 + q] = scD[0][q] + scD[1][q] + scD[2][q] + scD[3][q];
    }
}

// ================= K6: agg2 + classifier (fused) =================
// Same agg structure; rows stay f32 in LDS; classifier GEMM + log_softmax
// in-block (Wl 20 KB, L2-resident). Kills the hC round-trip.
__global__ __launch_bounds__(256) void k6_agg_cls(
        const uint32_t* __restrict__ h, const float* __restrict__ ssrc,
        const float* __restrict__ sdst, const int* __restrict__ rowptr,
        const int* __restrict__ adj, const float* __restrict__ bias,
        const float* __restrict__ Wl, const float* __restrict__ bl,
        float* __restrict__ out) {
    int tid = threadIdx.x;
    int wv = tid >> 6, lane = tid & 63;
    int sub = lane >> 4, l16 = lane & 15;
    int row0 = blockIdx.x * 16;
    __shared__ __align__(16) float wbuf[4][64];
    __shared__ __align__(16) int   sbuf[4][64];
    __shared__ float xs[16][FDIM];
    const uint4* h4 = (const uint4*)h;

    for (int i = 0; i < 4; i++) {
        int row = wv * 4 + i;
        int n = row0 + row;
        int beg = rowptr[n], deg = rowptr[n + 1] - beg;
        float acc[8] = {};
        float dsum = 0.f;
        wave_agg_loop(h4, ssrc, adj, sdst[n], beg, deg, wbuf[wv], sbuf[wv],
                      lane, sub, l16, acc, dsum);
        if (sub == 0) {
            float inv = 1.f / dsum;
            float4 b0 = *(const float4*)&bias[l16 * 8];
            float4 b1 = *(const float4*)&bias[l16 * 8 + 4];
            float4 p0, p1;
            p0.x = acc[0] * inv + b0.x; p0.y = acc[1] * inv + b0.y;
            p0.z = acc[2] * inv + b0.z; p0.w = acc[3] * inv + b0.w;
            p1.x = acc[4] * inv + b1.x; p1.y = acc[5] * inv + b1.y;
            p1.z = acc[6] * inv + b1.z; p1.w = acc[7] * inv + b1.w;
            *(float4*)&xs[row][l16 * 8]     = p0;
            *(float4*)&xs[row][l16 * 8 + 4] = p1;
        }
    }
    __syncthreads();

    // ---- classifier: wave hw handles rows hw*4..hw*4+3 ----
    int c = tid & 63, hw = tid >> 6;
    float acc[4];
    float blc = (c < NCLS) ? bl[c] : 0.f;
    #pragma unroll
    for (int r = 0; r < 4; r++) acc[r] = blc;

    #pragma unroll 2
    for (int k = 0; k < FDIM; k += 4) {
        float w0 = 0.f, w1 = 0.f, w2 = 0.f, w3 = 0.f;
        if (c < NCLS) {
            w0 = Wl[(k + 0) * NCLS + c]; w1 = Wl[(k + 1) * NCLS + c];
            w2 = Wl[(k + 2) * NCLS + c]; w3 = Wl[(k + 3) * NCLS + c];
        }
        #pragma unroll
        for (int r = 0; r < 4; r++) {
            float4 xv = *(const float4*)&xs[hw * 4 + r][k];
            acc[r] += xv.x * w0 + xv.y * w1 + xv.z * w2 + xv.w * w3;
        }
    }
    #pragma unroll
    for (int r = 0; r < 4; r++) {
        float v = (c < NCLS) ? acc[r] : -INFINITY;
        float mx = v;
        #pragma unroll
        for (int off = 32; off > 0; off >>= 1) mx = fmaxf(mx, __shfl_xor(mx, off, 64));
        float ex = (c < NCLS) ? expf(v - mx) : 0.f;
        #pragma unroll
        for (int off = 32; off > 0; off >>= 1) ex += __shfl_xor(ex, off, 64);
        float ls = logf(ex);
        if (c < NCLS) out[(size_t)(row0 + hw * 4 + r) * NCLS + c] = v - mx - ls;
    }
}

extern "C" void kernel_launch(void* const* d_in, const int* in_sizes, int n_in,
                              void* d_out, int out_size, void* d_ws, size_t ws_size,
                              hipStream_t stream) {
    const float* x   = (const float*)d_in[0];
    const int*   ei  = (const int*)d_in[1];
    const float* W1  = (const float*)d_in[2];
    const float* a1s = (const float*)d_in[3];
    const float* a1d = (const float*)d_in[4];
    const float* b1  = (const float*)d_in[5];
    const float* W2  = (const float*)d_in[6];
    const float* a2s = (const float*)d_in[7];
    const float* a2d = (const float*)d_in[8];
    const float* b2  = (const float*)d_in[9];
    const float* Wl  = (const float*)d_in[10];
    const float* bl  = (const float*)d_in[11];
    float* out = (float*)d_out;

    char* ws = (char*)d_ws;
    size_t off = 0;
    auto alloc = [&](size_t bytes) {
        void* p = ws + off;
        off = (off + bytes + 255) & ~(size_t)255;
        return p;
    };
    int*      row_ptr = (int*)alloc((N_NODES + 1) * sizeof(int));
    int*      cursor  = (int*)alloc(N_NODES * sizeof(int));
    int*      counts  = (int*)alloc(N_NODES * sizeof(int));
    int*      bsums   = (int*)alloc(64 * sizeof(int));
    int*      adj     = (int*)alloc(TOT_E * sizeof(int));
    uint32_t* Xp      = (uint32_t*)alloc((size_t)N_NODES * HROW * sizeof(uint32_t));
    uint32_t* hA      = (uint32_t*)alloc((size_t)N_NODES * HROW * sizeof(uint32_t));
    uint32_t* hB      = (uint32_t*)alloc((size_t)N_NODES * HROW * sizeof(uint32_t));
    float*    ssrc    = (float*)alloc(N_NODES * sizeof(float));
    float*    sdst    = (float*)alloc(N_NODES * sizeof(float));
    float*    ssrc2   = (float*)alloc(N_NODES * sizeof(float));
    float*    sdst2   = (float*)alloc(N_NODES * sizeof(float));
    uint32_t* wf1     = (uint32_t*)alloc(2048 * 4 * sizeof(uint32_t));
    uint32_t* wf2     = (uint32_t*)alloc(2048 * 4 * sizeof(uint32_t));

    // K0: zero the histogram (self loops folded into scan's +1)
    hipMemsetAsync(counts, 0, N_NODES * sizeof(int), stream);

    // K1: pack x ∥ prepack W frags ∥ histogram
    hipLaunchKernelGGL(k1_setup_hist, dim3(PACK_BLOCKS + WFRAG_BLOCKS + HIST_BLOCKS), dim3(256),
                       0, stream, x, Xp, W1, W2, wf1, wf2, ei, counts);

    // K2/K3: scan
    int nscan = (N_NODES + SCAN_B - 1) / SCAN_B;  // 49
    hipLaunchKernelGGL(scan1_kernel, dim3(nscan), dim3(SCAN_B), 0, stream, counts, row_ptr, bsums, N_NODES);
    hipLaunchKernelGGL(scan3_kernel, dim3(nscan), dim3(SCAN_B), 0, stream, row_ptr, bsums, cursor, N_NODES, TOT_E);

    // K4: scatter ∥ gemm1(+scores1) ∥ edge pass-through
    hipLaunchKernelGGL(k4_scatter_gemm_edge, dim3(SCAT_BLOCKS + GEMM_BLOCKS + EDGE_BLOCKS), dim3(256),
                       0, stream, ei, cursor, adj, Xp, wf1, a1s, a1d, hA, ssrc, sdst,
                       out + (size_t)N_NODES * NCLS);

    // K5: agg1 + gemm2 + scores2
    hipLaunchKernelGGL(k5_agg_gemm, dim3(N_NODES / 16), dim3(256), 0, stream,
                       hA, ssrc, sdst, row_ptr, adj, b1, wf2, a2s, a2d, hB, ssrc2, sdst2);

    // K6: agg2 + classifier
    hipLaunchKernelGGL(k6_agg_cls, dim3(N_NODES / 16), dim3(256), 0, stream,
                       hB, ssrc2, sdst2, row_ptr, adj, b2, Wl, bl, out);
}

// Round 9
// 269.160 us; speedup vs baseline: 1.6770x; 1.0615x over previous
//
#include <hip/hip_runtime.h>
#include <hip/hip_bf16.h>
#include <math.h>

#define N_NODES 50000
#define N_EDGES 600000
#define TOT_E   (N_EDGES + N_NODES)   // with self loops
#define FDIM    128
#define HROW    64                    // packed bf16 row: 64 uint32 = 128 bf16
#define NCLS    40
#define SCAN_B  1024

typedef __attribute__((ext_vector_type(4))) float  f32x4;
typedef __attribute__((ext_vector_type(8))) __bf16 bf16x8;
union FragU { uint32_t u[4]; bf16x8 v; };

// ---------------- bf16 pack/unpack (RNE) ----------------
__device__ inline float bf16_lo(uint32_t u) { return __uint_as_float(u << 16); }
__device__ inline float bf16_hi(uint32_t u) { return __uint_as_float(u & 0xffff0000u); }
__device__ inline uint32_t bf16_pack(float a, float b) {
    uint32_t ua = __float_as_uint(a), ub = __float_as_uint(b);
    uint32_t ra = (ua + 0x7fffu + ((ua >> 16) & 1u)) >> 16;
    uint32_t rb = (ub + 0x7fffu + ((ub >> 16) & 1u)) >> 16;
    return ra | (rb << 16);
}

// ---------------- per-wave aggregation inner loop (shared K5/K6) ----------------
// 16 lanes/row x uint4: 4 rows in flight per load instruction. The strip is
// PADDED to a multiple of 16 edges with (w=0, s=0) so the wide 4-load round is
// the ONLY path: avg deg~13 -> 1 round of 4 overlapped gathers instead of ~4
// serial load->use rounds (round-8 latency chain, VALUBusy 51%). No max pass
// (softmax shift-invariant; |e| <= ~10 here so exp(e) is f32-safe).
__device__ __forceinline__ void wave_agg_loop(
        const uint4* __restrict__ h4, const float* __restrict__ ssrc,
        const int* __restrict__ adj, float sd, int beg, int deg,
        float* wb, int* sb, int lane, int sub, int l16,
        float acc[8], float& dsum) {
    for (int base = 0; base < deg; base += 64) {
        int c = min(64, deg - base);
        int s = 0; float w = 0.f;
        if (lane < c) {
            s = adj[beg + base + lane];
            float e = ssrc[s] + sd;
            e = (e >= 0.f) ? e : 0.2f * e;
            w = __expf(e);
        }
        wb[lane] = w;
        sb[lane] = s;
        dsum += w;                                   // pad lanes add 0
        // wave-synchronous LDS: drain ds_writes before cross-lane reads.
        asm volatile("s_waitcnt lgkmcnt(0)" ::: "memory");

        int rounds = (c + 15) >> 4;
        for (int t = 0; t < rounds; t++) {           // 16 edges: 4 per sub-group
            int j = t * 16 + 4 * sub;
            float4 w4 = *(const float4*)&wb[j];
            int4   s4 = *(const int4*)&sb[j];
            uint4 u0 = h4[(size_t)s4.x * 16 + l16];
            uint4 u1 = h4[(size_t)s4.y * 16 + l16];
            uint4 u2 = h4[(size_t)s4.z * 16 + l16];
            uint4 u3 = h4[(size_t)s4.w * 16 + l16];
            acc[0] += w4.x * bf16_lo(u0.x) + w4.y * bf16_lo(u1.x) + w4.z * bf16_lo(u2.x) + w4.w * bf16_lo(u3.x);
            acc[1] += w4.x * bf16_hi(u0.x) + w4.y * bf16_hi(u1.x) + w4.z * bf16_hi(u2.x) + w4.w * bf16_hi(u3.x);
            acc[2] += w4.x * bf16_lo(u0.y) + w4.y * bf16_lo(u1.y) + w4.z * bf16_lo(u2.y) + w4.w * bf16_lo(u3.y);
            acc[3] += w4.x * bf16_hi(u0.y) + w4.y * bf16_hi(u1.y) + w4.z * bf16_hi(u2.y) + w4.w * bf16_hi(u3.y);
            acc[4] += w4.x * bf16_lo(u0.z) + w4.y * bf16_lo(u1.z) + w4.z * bf16_lo(u2.z) + w4.w * bf16_lo(u3.z);
            acc[5] += w4.x * bf16_hi(u0.z) + w4.y * bf16_hi(u1.z) + w4.z * bf16_hi(u2.z) + w4.w * bf16_hi(u3.z);
            acc[6] += w4.x * bf16_lo(u0.w) + w4.y * bf16_lo(u1.w) + w4.z * bf16_lo(u2.w) + w4.w * bf16_lo(u3.w);
            acc[7] += w4.x * bf16_hi(u0.w) + w4.y * bf16_hi(u1.w) + w4.z * bf16_hi(u2.w) + w4.w * bf16_hi(u3.w);
        }
        asm volatile("" ::: "memory");
    }
    // combine the 4 sub-group partial sums (same cols, different edges)
    #pragma unroll
    for (int k = 0; k < 8; k++) {
        acc[k] += __shfl_xor(acc[k], 16, 64);
        acc[k] += __shfl_xor(acc[k], 32, 64);
    }
    #pragma unroll
    for (int off = 32; off > 0; off >>= 1) dsum += __shfl_xor(dsum, off, 64);
}

// ================= K1: pack_x ∥ W-frag prepack ∥ hist =================
#define PACK_BLOCKS  12500                          // 3.2M dwords / 256
#define WFRAG_BLOCKS 16
#define HIST_BLOCKS  ((N_EDGES / 4 + 255) / 256)    // 586
__global__ __launch_bounds__(256) void k1_setup_hist(
        const float* __restrict__ x, uint32_t* __restrict__ Xp,
        const float* __restrict__ W1, const float* __restrict__ W2,
        uint32_t* __restrict__ wf1, uint32_t* __restrict__ wf2,
        const int* __restrict__ ei, int* __restrict__ counts) {
    int b = blockIdx.x;
    if (b < PACK_BLOCKS) {
        int i = b * 256 + threadIdx.x;
        float2 v = ((const float2*)x)[i];
        Xp[i] = bf16_pack(v.x, v.y);
        return;
    }
    if (b < PACK_BLOCKS + WFRAG_BLOCKS) {
        // lane holds W[k][n]: n = nt*16 + (lane&15), k = kt*32 + 4g + {e&3} + 16*(e>>2)
        int t = (b - PACK_BLOCKS) * 256 + threadIdx.x;    // 0..4095
        if (t >= 4096) return;
        const float* W = (t < 2048) ? W1 : W2;
        uint32_t*   wf = (t < 2048) ? wf1 : wf2;
        int q = t & 2047;
        int lane = q & 63, nt = (q >> 6) & 7, kt = q >> 9;
        int n = nt * 16 + (lane & 15), g = lane >> 4;
        uint32_t frag[4];
        #pragma unroll
        for (int d = 0; d < 4; d++) {
            int kb = kt * 32 + 4 * g + (d & 1) * 2 + (d >> 1) * 16;
            frag[d] = bf16_pack(W[kb * FDIM + n], W[(kb + 1) * FDIM + n]);
        }
        ((uint4*)wf)[(kt * 8 + nt) * 64 + lane] = *(uint4*)frag;
        return;
    }
    int i = (b - PACK_BLOCKS - WFRAG_BLOCKS) * 256 + threadIdx.x;
    if (i >= N_EDGES / 4) return;
    int4 d = ((const int4*)(ei + N_EDGES))[i];
    atomicAdd(&counts[d.x], 1);
    atomicAdd(&counts[d.y], 1);
    atomicAdd(&counts[d.z], 1);
    atomicAdd(&counts[d.w], 1);
}

// ================= K2/K3: scan =================
// shfl-based block scan; +1 folds the self loop in (counts memset to 0).
__global__ void scan1_kernel(const int* __restrict__ counts, int* __restrict__ excl,
                             int* __restrict__ bsums, int n) {
    __shared__ int ws[16];
    int gid = blockIdx.x * SCAN_B + threadIdx.x;
    int wv = threadIdx.x >> 6, lane = threadIdx.x & 63;
    int v = (gid < n) ? (counts[gid] + 1) : 0;
    int incl = v;
    #pragma unroll
    for (int off = 1; off < 64; off <<= 1) {
        int t = __shfl_up(incl, off, 64);
        if (lane >= off) incl += t;
    }
    if (lane == 63) ws[wv] = incl;
    __syncthreads();
    int woff = 0;
    for (int i = 0; i < wv; i++) woff += ws[i];
    if (gid < n) excl[gid] = woff + incl - v;
    if (threadIdx.x == SCAN_B - 1) bsums[blockIdx.x] = woff + incl;
}

__global__ void scan3_kernel(int* __restrict__ rowptr, const int* __restrict__ bsums,
                             int* __restrict__ cursor, int n, int total) {
    __shared__ int base_s;
    if (threadIdx.x < 64) {
        int v = (threadIdx.x < (int)blockIdx.x) ? bsums[threadIdx.x] : 0;
        #pragma unroll
        for (int off = 32; off > 0; off >>= 1) v += __shfl_down(v, off, 64);
        if (threadIdx.x == 0) base_s = v;
    }
    __syncthreads();
    int base = base_s;
    int gid = blockIdx.x * SCAN_B + threadIdx.x;
    if (gid < n) {
        int v = rowptr[gid] + base;
        rowptr[gid] = v;
        cursor[gid] = v;
    }
    if (gid == 0) rowptr[n] = total;
}

// ================= K4: scatter ∥ mfma_gemm1(+scores1) ∥ edge copy =================
#define SCAT_T      ((N_EDGES / 4) + N_NODES)       // 200000
#define SCAT_BLOCKS ((SCAT_T + 255) / 256)          // 782
#define GEMM_BLOCKS ((N_NODES + 63) / 64)           // 782
#define EDGE_ITEMS  ((2 * N_EDGES) / 4)             // 300000 int4
#define EDGE_BLOCKS ((EDGE_ITEMS + 255) / 256)      // 1172
__global__ __launch_bounds__(256) void k4_scatter_gemm_edge(
        const int* __restrict__ ei, int* __restrict__ cursor, int* __restrict__ adj,
        const uint32_t* __restrict__ Xp, const uint32_t* __restrict__ wf,
        const float* __restrict__ a_s, const float* __restrict__ a_d,
        uint32_t* __restrict__ H, float* __restrict__ ssrc, float* __restrict__ sdst,
        float* __restrict__ eout) {
    int b = blockIdx.x;
    if (b < SCAT_BLOCKS) {
        int i = b * 256 + threadIdx.x;
        if (i >= SCAT_T) return;
        if (i < N_EDGES / 4) {
            int4 s4 = ((const int4*)ei)[i];
            int4 d4 = ((const int4*)(ei + N_EDGES))[i];
            adj[atomicAdd(&cursor[d4.x], 1)] = s4.x;
            adj[atomicAdd(&cursor[d4.y], 1)] = s4.y;
            adj[atomicAdd(&cursor[d4.z], 1)] = s4.z;
            adj[atomicAdd(&cursor[d4.w], 1)] = s4.w;
        } else {
            int nd = i - N_EDGES / 4;
            adj[atomicAdd(&cursor[nd], 1)] = nd;
        }
        return;
    }
    if (b < SCAT_BLOCKS + GEMM_BLOCKS) {
        // 4 waves/block, each wave a 16-row x 128-col band; 32 MFMAs/wave.
        int lane = threadIdx.x & 63, wv = threadIdx.x >> 6;
        int row0 = (b - SCAT_BLOCKS) * 64 + wv * 16;
        if (row0 >= N_NODES) return;
        int r = lane & 15, g = lane >> 4;

        const uint32_t* xrow = Xp + (size_t)(row0 + r) * HROW + 2 * g;
        FragU af[4];
        #pragma unroll
        for (int kt = 0; kt < 4; kt++) {
            uint2 lo = *(const uint2*)(xrow + kt * 16);
            uint2 hi = *(const uint2*)(xrow + kt * 16 + 8);
            af[kt].u[0] = lo.x; af[kt].u[1] = lo.y;
            af[kt].u[2] = hi.x; af[kt].u[3] = hi.y;
        }
        f32x4 acc[8] = {};
        #pragma unroll
        for (int kt = 0; kt < 4; kt++) {
            #pragma unroll
            for (int nt = 0; nt < 8; nt++) {
                FragU bfr;
                *(uint4*)bfr.u = ((const uint4*)wf)[(kt * 8 + nt) * 64 + lane];
                acc[nt] = __builtin_amdgcn_mfma_f32_16x16x32_bf16(af[kt].v, bfr.v, acc[nt], 0, 0, 0);
            }
        }
        // fused scores: D layout lane holds D[4g+j][16*nt+r]
        float av_s[8], av_d[8];
        #pragma unroll
        for (int nt = 0; nt < 8; nt++) { av_s[nt] = a_s[16 * nt + r]; av_d[nt] = a_d[16 * nt + r]; }
        #pragma unroll
        for (int j = 0; j < 4; j++) {
            float ps = 0.f, pd = 0.f;
            #pragma unroll
            for (int nt = 0; nt < 8; nt++) { ps += acc[nt][j] * av_s[nt]; pd += acc[nt][j] * av_d[nt]; }
            #pragma unroll
            for (int off = 1; off < 16; off <<= 1) {
                ps += __shfl_xor(ps, off, 64);
                pd += __shfl_xor(pd, off, 64);
            }
            if (r == 0) { ssrc[row0 + 4 * g + j] = ps; sdst[row0 + 4 * g + j] = pd; }
        }
        // pack to bf16: col pairs via shfl_xor(1)
        #pragma unroll
        for (int nt = 0; nt < 8; nt++) {
            #pragma unroll
            for (int j = 0; j < 4; j++) {
                float v0 = acc[nt][j];
                float v1 = __shfl_xor(v0, 1, 64);
                if (!(r & 1))
                    H[(size_t)(row0 + 4 * g + j) * HROW + nt * 8 + (r >> 1)] = bf16_pack(v0, v1);
            }
        }
        return;
    }
    int i = (b - SCAT_BLOCKS - GEMM_BLOCKS) * 256 + threadIdx.x;
    if (i < EDGE_ITEMS) {
        int4 v = ((const int4*)ei)[i];
        ((float4*)eout)[i] = make_float4((float)v.x, (float)v.y, (float)v.z, (float)v.w);
    }
}

// ================= K5: agg1 + gemm2 + scores2 (fused) =================
// Block = 4 waves = 16 nodes. Each wave aggregates 4 nodes sequentially into
// LDS rowbuf (bf16), then the block MFMAs the 16-row tile with wf2 and reduces
// next-layer attention scores in LDS. Kills the hB round-trip.
__global__ __launch_bounds__(256) void k5_agg_gemm(
        const uint32_t* __restrict__ h, const float* __restrict__ ssrc,
        const float* __restrict__ sdst, const int* __restrict__ rowptr,
        const int* __restrict__ adj, const float* __restrict__ bias,
        const uint32_t* __restrict__ wf, const float* __restrict__ a_s,
        const float* __restrict__ a_d, uint32_t* __restrict__ Hout,
        float* __restrict__ ssrc2, float* __restrict__ sdst2) {
    int tid = threadIdx.x;
    int wv = tid >> 6, lane = tid & 63;
    int sub = lane >> 4, l16 = lane & 15;
    int row0 = blockIdx.x * 16;
    __shared__ __align__(16) float    wbuf[4][64];
    __shared__ __align__(16) int      sbuf[4][64];
    __shared__ __align__(16) uint32_t rowbuf[16][68];   // 64 data + 4 pad dwords
    __shared__ float scS[4][16], scD[4][16];
    const uint4* h4 = (const uint4*)h;

    for (int i = 0; i < 4; i++) {
        int row = wv * 4 + i;
        int n = row0 + row;
        int beg = rowptr[n], deg = rowptr[n + 1] - beg;  // >= 1 (self loop)
        float acc[8] = {};
        float dsum = 0.f;
        wave_agg_loop(h4, ssrc, adj, sdst[n], beg, deg, wbuf[wv], sbuf[wv],
                      lane, sub, l16, acc, dsum);
        if (sub == 0) {
            float inv = 1.f / dsum;
            float4 b0 = *(const float4*)&bias[l16 * 8];
            float4 b1 = *(const float4*)&bias[l16 * 8 + 4];
            float v0 = fmaxf(acc[0] * inv + b0.x, 0.f), v1 = fmaxf(acc[1] * inv + b0.y, 0.f);
            float v2 = fmaxf(acc[2] * inv + b0.z, 0.f), v3 = fmaxf(acc[3] * inv + b0.w, 0.f);
            float v4 = fmaxf(acc[4] * inv + b1.x, 0.f), v5 = fmaxf(acc[5] * inv + b1.y, 0.f);
            float v6 = fmaxf(acc[6] * inv + b1.z, 0.f), v7 = fmaxf(acc[7] * inv + b1.w, 0.f);
            uint4 o;
            o.x = bf16_pack(v0, v1); o.y = bf16_pack(v2, v3);
            o.z = bf16_pack(v4, v5); o.w = bf16_pack(v6, v7);
            *(uint4*)&rowbuf[row][l16 * 4] = o;
        }
    }
    __syncthreads();

    // ---- phase 2: 16x128 GEMM tile, wave wv owns nt = 2wv, 2wv+1 ----
    int r = lane & 15, g = lane >> 4;
    FragU af[4];
    #pragma unroll
    for (int kt = 0; kt < 4; kt++) {
        uint2 lo = *(const uint2*)&rowbuf[r][kt * 16 + 2 * g];
        uint2 hi = *(const uint2*)&rowbuf[r][kt * 16 + 2 * g + 8];
        af[kt].u[0] = lo.x; af[kt].u[1] = lo.y;
        af[kt].u[2] = hi.x; af[kt].u[3] = hi.y;
    }
    f32x4 acc2[2] = {};
    #pragma unroll
    for (int kt = 0; kt < 4; kt++) {
        #pragma unroll
        for (int t = 0; t < 2; t++) {
            int nt = 2 * wv + t;
            FragU bfr;
            *(uint4*)bfr.u = ((const uint4*)wf)[(kt * 8 + nt) * 64 + lane];
            acc2[t] = __builtin_amdgcn_mfma_f32_16x16x32_bf16(af[kt].v, bfr.v, acc2[t], 0, 0, 0);
        }
    }
    // ---- phase 3: score partials (this wave's 32 cols), cross-wave via LDS ----
    float as0 = a_s[16 * (2 * wv) + r], as1 = a_s[16 * (2 * wv + 1) + r];
    float ad0 = a_d[16 * (2 * wv) + r], ad1 = a_d[16 * (2 * wv + 1) + r];
    #pragma unroll
    for (int j = 0; j < 4; j++) {
        float ps = acc2[0][j] * as0 + acc2[1][j] * as1;
        float pd = acc2[0][j] * ad0 + acc2[1][j] * ad1;
        #pragma unroll
        for (int off = 1; off < 16; off <<= 1) {
            ps += __shfl_xor(ps, off, 64);
            pd += __shfl_xor(pd, off, 64);
        }
        if (r == 0) { scS[wv][4 * g + j] = ps; scD[wv][4 * g + j] = pd; }
    }
    // ---- phase 4: bf16 pack + global H write (cols 32wv..32wv+31) ----
    #pragma unroll
    for (int t = 0; t < 2; t++) {
        #pragma unroll
        for (int j = 0; j < 4; j++) {
            float v0 = acc2[t][j];
            float v1 = __shfl_xor(v0, 1, 64);
            if (!(r & 1))
                Hout[(size_t)(row0 + 4 * g + j) * HROW + (2 * wv + t) * 8 + (r >> 1)] = bf16_pack(v0, v1);
        }
    }
    __syncthreads();
    if (tid < 16)
        ssrc2[row0 + tid] = scS[0][tid] + scS[1][tid] + scS[2][tid] + scS[3][tid];
    else if (tid < 32) {
        int q = tid - 16;
        sdst2[row0 + q] = scD[0][q] + scD[1][q] + scD[2][q] + scD[3][q];
    }
}

// ================= K6: agg2 + classifier (fused) =================
// Same agg structure; rows stay f32 in LDS; classifier GEMM + log_softmax
// in-block (Wl 20 KB, L2-resident). Kills the hC round-trip.
__global__ __launch_bounds__(256) void k6_agg_cls(
        const uint32_t* __restrict__ h, const float* __restrict__ ssrc,
        const float* __restrict__ sdst, const int* __restrict__ rowptr,
        const int* __restrict__ adj, const float* __restrict__ bias,
        const float* __restrict__ Wl, const float* __restrict__ bl,
        float* __restrict__ out) {
    int tid = threadIdx.x;
    int wv = tid >> 6, lane = tid & 63;
    int sub = lane >> 4, l16 = lane & 15;
    int row0 = blockIdx.x * 16;
    __shared__ __align__(16) float wbuf[4][64];
    __shared__ __align__(16) int   sbuf[4][64];
    __shared__ float xs[16][FDIM];
    const uint4* h4 = (const uint4*)h;

    for (int i = 0; i < 4; i++) {
        int row = wv * 4 + i;
        int n = row0 + row;
        int beg = rowptr[n], deg = rowptr[n + 1] - beg;
        float acc[8] = {};
        float dsum = 0.f;
        wave_agg_loop(h4, ssrc, adj, sdst[n], beg, deg, wbuf[wv], sbuf[wv],
                      lane, sub, l16, acc, dsum);
        if (sub == 0) {
            float inv = 1.f / dsum;
            float4 b0 = *(const float4*)&bias[l16 * 8];
            float4 b1 = *(const float4*)&bias[l16 * 8 + 4];
            float4 p0, p1;
            p0.x = acc[0] * inv + b0.x; p0.y = acc[1] * inv + b0.y;
            p0.z = acc[2] * inv + b0.z; p0.w = acc[3] * inv + b0.w;
            p1.x = acc[4] * inv + b1.x; p1.y = acc[5] * inv + b1.y;
            p1.z = acc[6] * inv + b1.z; p1.w = acc[7] * inv + b1.w;
            *(float4*)&xs[row][l16 * 8]     = p0;
            *(float4*)&xs[row][l16 * 8 + 4] = p1;
        }
    }
    __syncthreads();

    // ---- classifier: wave hw handles rows hw*4..hw*4+3 ----
    int c = tid & 63, hw = tid >> 6;
    float acc[4];
    float blc = (c < NCLS) ? bl[c] : 0.f;
    #pragma unroll
    for (int r = 0; r < 4; r++) acc[r] = blc;

    #pragma unroll 2
    for (int k = 0; k < FDIM; k += 4) {
        float w0 = 0.f, w1 = 0.f, w2 = 0.f, w3 = 0.f;
        if (c < NCLS) {
            w0 = Wl[(k + 0) * NCLS + c]; w1 = Wl[(k + 1) * NCLS + c];
            w2 = Wl[(k + 2) * NCLS + c]; w3 = Wl[(k + 3) * NCLS + c];
        }
        #pragma unroll
        for (int r = 0; r < 4; r++) {
            float4 xv = *(const float4*)&xs[hw * 4 + r][k];
            acc[r] += xv.x * w0 + xv.y * w1 + xv.z * w2 + xv.w * w3;
        }
    }
    #pragma unroll
    for (int r = 0; r < 4; r++) {
        float v = (c < NCLS) ? acc[r] : -INFINITY;
        float mx = v;
        #pragma unroll
        for (int off = 32; off > 0; off >>= 1) mx = fmaxf(mx, __shfl_xor(mx, off, 64));
        float ex = (c < NCLS) ? expf(v - mx) : 0.f;
        #pragma unroll
        for (int off = 32; off > 0; off >>= 1) ex += __shfl_xor(ex, off, 64);
        float ls = logf(ex);
        if (c < NCLS) out[(size_t)(row0 + hw * 4 + r) * NCLS + c] = v - mx - ls;
    }
}

extern "C" void kernel_launch(void* const* d_in, const int* in_sizes, int n_in,
                              void* d_out, int out_size, void* d_ws, size_t ws_size,
                              hipStream_t stream) {
    const float* x   = (const float*)d_in[0];
    const int*   ei  = (const int*)d_in[1];
    const float* W1  = (const float*)d_in[2];
    const float* a1s = (const float*)d_in[3];
    const float* a1d = (const float*)d_in[4];
    const float* b1  = (const float*)d_in[5];
    const float* W2  = (const float*)d_in[6];
    const float* a2s = (const float*)d_in[7];
    const float* a2d = (const float*)d_in[8];
    const float* b2  = (const float*)d_in[9];
    const float* Wl  = (const float*)d_in[10];
    const float* bl  = (const float*)d_in[11];
    float* out = (float*)d_out;

    char* ws = (char*)d_ws;
    size_t off = 0;
    auto alloc = [&](size_t bytes) {
        void* p = ws + off;
        off = (off + bytes + 255) & ~(size_t)255;
        return p;
    };
    int*      row_ptr = (int*)alloc((N_NODES + 1) * sizeof(int));
    int*      cursor  = (int*)alloc(N_NODES * sizeof(int));
    int*      counts  = (int*)alloc(N_NODES * sizeof(int));
    int*      bsums   = (int*)alloc(64 * sizeof(int));
    int*      adj     = (int*)alloc(TOT_E * sizeof(int));
    uint32_t* Xp      = (uint32_t*)alloc((size_t)N_NODES * HROW * sizeof(uint32_t));
    uint32_t* hA      = (uint32_t*)alloc((size_t)N_NODES * HROW * sizeof(uint32_t));
    uint32_t* hB      = (uint32_t*)alloc((size_t)N_NODES * HROW * sizeof(uint32_t));
    float*    ssrc    = (float*)alloc(N_NODES * sizeof(float));
    float*    sdst    = (float*)alloc(N_NODES * sizeof(float));
    float*    ssrc2   = (float*)alloc(N_NODES * sizeof(float));
    float*    sdst2   = (float*)alloc(N_NODES * sizeof(float));
    uint32_t* wf1     = (uint32_t*)alloc(2048 * 4 * sizeof(uint32_t));
    uint32_t* wf2     = (uint32_t*)alloc(2048 * 4 * sizeof(uint32_t));

    // K0: zero the histogram (self loops folded into scan's +1)
    hipMemsetAsync(counts, 0, N_NODES * sizeof(int), stream);

    // K1: pack x ∥ prepack W frags ∥ histogram
    hipLaunchKernelGGL(k1_setup_hist, dim3(PACK_BLOCKS + WFRAG_BLOCKS + HIST_BLOCKS), dim3(256),
                       0, stream, x, Xp, W1, W2, wf1, wf2, ei, counts);

    // K2/K3: scan
    int nscan = (N_NODES + SCAN_B - 1) / SCAN_B;  // 49
    hipLaunchKernelGGL(scan1_kernel, dim3(nscan), dim3(SCAN_B), 0, stream, counts, row_ptr, bsums, N_NODES);
    hipLaunchKernelGGL(scan3_kernel, dim3(nscan), dim3(SCAN_B), 0, stream, row_ptr, bsums, cursor, N_NODES, TOT_E);

    // K4: scatter ∥ gemm1(+scores1) ∥ edge pass-through
    hipLaunchKernelGGL(k4_scatter_gemm_edge, dim3(SCAT_BLOCKS + GEMM_BLOCKS + EDGE_BLOCKS), dim3(256),
                       0, stream, ei, cursor, adj, Xp, wf1, a1s, a1d, hA, ssrc, sdst,
                       out + (size_t)N_NODES * NCLS);

    // K5: agg1 + gemm2 + scores2
    hipLaunchKernelGGL(k5_agg_gemm, dim3(N_NODES / 16), dim3(256), 0, stream,
                       hA, ssrc, sdst, row_ptr, adj, b1, wf2, a2s, a2d, hB, ssrc2, sdst2);

    // K6: agg2 + classifier
    hipLaunchKernelGGL(k6_agg_cls, dim3(N_NODES / 16), dim3(256), 0, stream,
                       hB, ssrc2, sdst2, row_ptr, adj, b2, Wl, bl, out);
}